// Round 1
// baseline (317.921 us; speedup 1.0000x reference)
//
#include <hip/hip_runtime.h>
#include <stdint.h>

#define HH   512
#define WW   1024
#define BB   2
#define NCC  34
#define PADK 7
#define TOPK 200
#define NSEG (TOPK + 1)
#define WPAD (WW + 2 * PADK)   // 1038
#define NPIX (HH * WW)         // 524288
#define CAP  12288
#define INTMAXC  0x7FFFFFFF
#define INTMINC  (-0x7FFFFFFF - 1)

// ---------------- K0: init min/max stat arrays ----------------
__global__ void k_init_minmax(int* __restrict__ y0, int* __restrict__ y1,
                              int* __restrict__ x0, int* __restrict__ x1) {
  int i = blockIdx.x * blockDim.x + threadIdx.x;
  if (i < BB * NSEG) { y0[i] = INTMAXC; y1[i] = INTMINC; x0[i] = INTMAXC; x1[i] = INTMINC; }
}

// ---------------- K1: per-pixel fused pass ----------------
// argmax class, softmax max + 1/sumexp, seg_map output, vote scatter
__global__ __launch_bounds__(256) void k_pixel(const float* __restrict__ seg,
    const float* __restrict__ cr, float* __restrict__ out_segmap,
    uint32_t* __restrict__ vote, float* __restrict__ mbuf,
    float* __restrict__ invs, uint8_t* __restrict__ segc) {
  int i = blockIdx.x * 256 + threadIdx.x;          // [0, BB*NPIX)
  int b = i / NPIX, p = i - b * NPIX;
  int h = p / WW, w = p - h * WW;
  const float* base = seg + (size_t)b * NCC * NPIX + p;
  float v[NCC];
  float mx = base[0]; int am = 0;
  v[0] = mx;
  #pragma unroll
  for (int c = 1; c < NCC; ++c) {
    float x = base[(size_t)c * NPIX];
    v[c] = x;
    if (x > mx) { mx = x; am = c; }                // first-max tie-break (strict >)
  }
  float s = 0.f;
  #pragma unroll
  for (int c = 0; c < NCC; ++c) s += expf(v[c] - mx);
  out_segmap[i] = (float)am;
  segc[i] = (uint8_t)am;
  mbuf[i] = mx;
  invs[i] = 1.f / s;
  if (am >= 24) {                                  // "things": class in (23.99, 33]
    float ccx = (float)(w + 1) - cr[(size_t)b * 2 * NPIX + p];
    float ccy = (float)(h + 1) - cr[(size_t)b * 2 * NPIX + NPIX + p];
    float rx = rintf(ccx), ry = rintf(ccy);        // matches jnp.round (half-to-even)
    if (rx >= 0.f && ry >= 0.f && rx < (float)WW && ry < (float)HH)
      atomicAdd(&vote[b * NPIX + (int)ry * WW + (int)rx], 1u);
  }
}

// ---------------- K2: 7x7 NMS, collect candidates ----------------
__global__ __launch_bounds__(256) void k_nms(const uint32_t* __restrict__ vote,
    uint32_t* __restrict__ cand_cnt, uint32_t* __restrict__ cand_val,
    uint32_t* __restrict__ cand_idx) {
  int i = blockIdx.x * 256 + threadIdx.x;
  int b = i / NPIX, p = i - b * NPIX;
  int h = p / WW, w = p - h * WW;
  uint32_t v = vote[i];
  if (v <= 50u) return;                            // nms > 50.0 <=> count >= 51
  const uint32_t* vb = vote + (size_t)b * NPIX;
  for (int dy = -3; dy <= 3; ++dy) {
    int yy = h + dy; if (yy < 0 || yy >= HH) continue;
    for (int dx = -3; dx <= 3; ++dx) {
      int xx = w + dx; if (xx < 0 || xx >= WW) continue;
      if (vb[yy * WW + xx] > v) return;            // strictly-greater disqualifies (ties kept)
    }
  }
  uint32_t pos = atomicAdd(&cand_cnt[b], 1u);
  if (pos < CAP) {
    cand_val[b * CAP + pos] = v;
    cand_idx[b * CAP + pos] = (uint32_t)((h + PADK) * WPAD + (w + PADK));  // PADDED coords
  }
}

// ---------------- K3: top-200 select with lax.top_k tie order ----------------
__global__ void k_topk(const uint32_t* __restrict__ cand_cnt,
    const uint32_t* __restrict__ cand_val, const uint32_t* __restrict__ cand_idx,
    float* __restrict__ slotx, float* __restrict__ sloty,
    int* __restrict__ slotlab, int* __restrict__ gn0) {
  int b = blockIdx.x;
  int n = (int)cand_cnt[b]; if (n > CAP) n = CAP;
  const uint32_t* cv = cand_val + b * CAP;
  const uint32_t* ci = cand_idx + b * CAP;
  for (int i = threadIdx.x; i < n; i += blockDim.x) {
    unsigned long long ki = ((unsigned long long)cv[i] << 20) | (unsigned long long)(0xFFFFFu - ci[i]);
    int r = 0;
    for (int j = 0; j < n; ++j) {
      unsigned long long kj = ((unsigned long long)cv[j] << 20) | (unsigned long long)(0xFFFFFu - ci[j]);
      r += (kj > ki) ? 1 : 0;                      // value desc, index asc (keys unique)
    }
    if (r < TOPK) {
      uint32_t idx = ci[i];
      slotx[b * TOPK + r] = (float)(idx % WPAD);   // cx = ti % Wp
      sloty[b * TOPK + r] = (float)(idx / WPAD);   // cy = ti // Wp
      slotlab[b * TOPK + r] = r + 1;
    }
  }
  if (threadIdx.x == 0) gn0[b] = (n < TOPK) ? n : TOPK;
}

// ---------------- K4/K7/K10: nearest-center assignment ----------------
__global__ __launch_bounds__(256) void k_assign(const float* __restrict__ cr,
    const uint8_t* __restrict__ segc, const float* __restrict__ cx,
    const float* __restrict__ cy, const int* __restrict__ clab,
    const int* __restrict__ ncent, const int* __restrict__ fallback,
    int* __restrict__ outlab) {
  int b = blockIdx.y;
  __shared__ float sxs[TOPK], sys[TOPK];
  __shared__ int   sls[TOPK];
  int n = ncent[b];
  for (int k = threadIdx.x; k < n; k += 256) {
    sxs[k] = cx[b * TOPK + k]; sys[k] = cy[b * TOPK + k]; sls[k] = clab[b * TOPK + k];
  }
  __syncthreads();
  int p = blockIdx.x * 256 + threadIdx.x;
  size_t i = (size_t)b * NPIX + p;
  if (n == 0) { outlab[i] = fallback ? fallback[i] : 0; return; }
  if (segc[i] < 24) { outlab[i] = 0; return; }
  int h = p / WW, w = p - h * WW;
  float ccx = (float)(w + 1) - cr[(size_t)b * 2 * NPIX + p];
  float ccy = (float)(h + 1) - cr[(size_t)b * 2 * NPIX + NPIX + p];
  float bd = 3.4e38f; int bi = 0;
  for (int k = 0; k < n; ++k) {
    float dx = ccx - sxs[k], dy = ccy - sys[k];
    // explicit mul+add (no FMA contraction) to bit-match the numpy reference
    float d = __fadd_rn(__fmul_rn(dx, dx), __fmul_rn(dy, dy));
    if (d < bd) { bd = d; bi = k; }                // strict <: earliest slot wins ties
  }
  outlab[i] = sls[bi];
}

// ---------------- K5: per-label count + bbox (labels >= 1 only) ----------------
__global__ __launch_bounds__(256) void k_stats1(const int* __restrict__ lab,
    uint32_t* __restrict__ gcnt, int* __restrict__ gy0, int* __restrict__ gy1,
    int* __restrict__ gx0, int* __restrict__ gx1) {
  int b = blockIdx.y;
  __shared__ uint32_t sc[NSEG];
  __shared__ int sy0[NSEG], sy1[NSEG], sx0[NSEG], sx1[NSEG];
  for (int j = threadIdx.x; j < NSEG; j += 256) {
    sc[j] = 0; sy0[j] = INTMAXC; sy1[j] = INTMINC; sx0[j] = INTMAXC; sx1[j] = INTMINC;
  }
  __syncthreads();
  int t = blockIdx.x * 256 + threadIdx.x;
  int p0 = t * 64;
  const int* lp = lab + (size_t)b * NPIX;
  int h = p0 / WW, wb = p0 - h * WW;               // 64-chunk stays inside one row
  int lA = -1, lB = -1; uint32_t cA = 0, cB = 0; int aA = 0, bA = 0, aB = 0, bB = 0;
  for (int q = 0; q < 64; q += 4) {
    int4 l4 = *reinterpret_cast<const int4*>(lp + p0 + q);
    int ls[4] = {l4.x, l4.y, l4.z, l4.w};
    #pragma unroll
    for (int r = 0; r < 4; ++r) {
      int l = ls[r];
      if (l == 0) continue;                        // label-0 stats unused by g1
      int x = wb + q + r;
      if (l == lA) { cA++; bA = x; }
      else if (l == lB) { cB++; bB = x; }
      else if (lA < 0) { lA = l; cA = 1; aA = bA = x; }
      else if (lB < 0) { lB = l; cB = 1; aB = bB = x; }
      else {
        atomicAdd(&sc[l], 1u);
        atomicMin(&sy0[l], h); atomicMax(&sy1[l], h);
        atomicMin(&sx0[l], x); atomicMax(&sx1[l], x);
      }
    }
  }
  if (lA >= 0) { atomicAdd(&sc[lA], cA); atomicMin(&sy0[lA], h); atomicMax(&sy1[lA], h);
                 atomicMin(&sx0[lA], aA); atomicMax(&sx1[lA], bA); }
  if (lB >= 0) { atomicAdd(&sc[lB], cB); atomicMin(&sy0[lB], h); atomicMax(&sy1[lB], h);
                 atomicMin(&sx0[lB], aB); atomicMax(&sx1[lB], bB); }
  __syncthreads();
  for (int j = threadIdx.x; j < NSEG; j += 256) {
    uint32_t c = sc[j];
    if (c) {
      atomicAdd(&gcnt[b * NSEG + j], c);
      atomicMin(&gy0[b * NSEG + j], sy0[j]); atomicMax(&gy1[b * NSEG + j], sy1[j]);
      atomicMin(&gx0[b * NSEG + j], sx0[j]); atomicMax(&gx1[b * NSEG + j], sx1[j]);
    }
  }
}

// ---------------- K6: bbox-ratio pruning -> compact list 1 ----------------
__global__ void k_build1(const uint32_t* __restrict__ gcnt, const int* __restrict__ gy0,
    const int* __restrict__ gy1, const int* __restrict__ gx0, const int* __restrict__ gx1,
    const float* __restrict__ slotx, const float* __restrict__ sloty,
    float* __restrict__ lx, float* __restrict__ ly, int* __restrict__ llab,
    int* __restrict__ gn) {
  int b = blockIdx.x;
  __shared__ int good[TOPK];
  __shared__ int pref[TOPK];
  int k = threadIdx.x;
  if (k < TOPK) {
    uint32_t c = gcnt[b * NSEG + k + 1];
    int g = 0;
    if (c > 0) {
      int j = b * NSEG + k + 1;
      float area = (float)((gy1[j] - gy0[j] + 1) * (gx1[j] - gx0[j] + 1));  // exact (< 2^24)
      float ratio = (float)c / area;               // same IEEE div as reference
      g = (ratio > 0.3f) ? 1 : 0;
    }
    good[k] = g;
  }
  __syncthreads();
  if (threadIdx.x == 0) {
    int s = 0;
    for (int j = 0; j < TOPK; ++j) { pref[j] = s; s += good[j]; }
    gn[b] = s;
  }
  __syncthreads();
  if (k < TOPK && good[k]) {
    int r = pref[k];
    lx[b * TOPK + r] = slotx[b * TOPK + k];
    ly[b * TOPK + r] = sloty[b * TOPK + k];
    llab[b * TOPK + r] = r + 1;                    // cumsum relabel
  }
}

// ---------------- K8: per-label count + fixed-point cr sums ----------------
__global__ __launch_bounds__(256) void k_stats2(const int* __restrict__ lab,
    const float* __restrict__ cr, uint32_t* __restrict__ gcnt,
    long long* __restrict__ gsx, long long* __restrict__ gsy) {
  int b = blockIdx.y;
  __shared__ uint32_t sc[NSEG];
  __shared__ unsigned long long ssx[NSEG], ssy[NSEG];
  for (int j = threadIdx.x; j < NSEG; j += 256) { sc[j] = 0; ssx[j] = 0; ssy[j] = 0; }
  __syncthreads();
  int t = blockIdx.x * 256 + threadIdx.x;
  int p0 = t * 64;
  const int* lp = lab + (size_t)b * NPIX;
  const float* c0 = cr + (size_t)b * 2 * NPIX;
  const float* c1 = c0 + NPIX;
  int lA = -1, lB = -1; uint32_t cA = 0, cB = 0;
  long long xA = 0, yA = 0, xB = 0, yB = 0;
  for (int q = 0; q < 64; ++q) {
    int p = p0 + q;
    int l = lp[p];
    if (l == 0) continue;                          // label-0 unused by g2
    long long qx = __double2ll_rn((double)c0[p] * 1048576.0);   // 2^20 fixed-point
    long long qy = __double2ll_rn((double)c1[p] * 1048576.0);
    if (l == lA) { cA++; xA += qx; yA += qy; }
    else if (l == lB) { cB++; xB += qx; yB += qy; }
    else if (lA < 0) { lA = l; cA = 1; xA = qx; yA = qy; }
    else if (lB < 0) { lB = l; cB = 1; xB = qx; yB = qy; }
    else { atomicAdd(&sc[l], 1u); atomicAdd(&ssx[l], (unsigned long long)qx);
           atomicAdd(&ssy[l], (unsigned long long)qy); }
  }
  if (lA >= 0) { atomicAdd(&sc[lA], cA); atomicAdd(&ssx[lA], (unsigned long long)xA);
                 atomicAdd(&ssy[lA], (unsigned long long)yA); }
  if (lB >= 0) { atomicAdd(&sc[lB], cB); atomicAdd(&ssx[lB], (unsigned long long)xB);
                 atomicAdd(&ssy[lB], (unsigned long long)yB); }
  __syncthreads();
  for (int j = threadIdx.x; j < NSEG; j += 256) {
    if (sc[j]) {
      atomicAdd(&gcnt[b * NSEG + j], sc[j]);
      atomicAdd((unsigned long long*)&gsx[b * NSEG + j], ssx[j]);
      atomicAdd((unsigned long long*)&gsy[b * NSEG + j], ssy[j]);
    }
  }
}

// ---------------- K9: mean pruning -> compact list 2 (ORIGINAL slot coords) ----------------
__global__ void k_build2(const uint32_t* __restrict__ gcnt, const long long* __restrict__ gsx,
    const long long* __restrict__ gsy, const float* __restrict__ slotx,
    const float* __restrict__ sloty, float* __restrict__ lx, float* __restrict__ ly,
    int* __restrict__ llab, int* __restrict__ gn) {
  int b = blockIdx.x;
  __shared__ int good[TOPK];
  __shared__ int pref[TOPK];
  int k = threadIdx.x;
  if (k < TOPK) {
    uint32_t c = gcnt[b * NSEG + k + 1];           // stats are in COMPACT label space
    int g = 0;
    if (c > 0) {
      double inv = 1.0 / (double)c;
      double mx = ((double)gsx[b * NSEG + k + 1] * (1.0 / 1048576.0)) * inv;
      double my = ((double)gsy[b * NSEG + k + 1] * (1.0 / 1048576.0)) * inv;
      g = (fabs(mx) < 10.0 && fabs(my) < 10.0) ? 1 : 0;
    }
    good[k] = g;
  }
  __syncthreads();
  if (threadIdx.x == 0) {
    int s = 0;
    for (int j = 0; j < TOPK; ++j) { pref[j] = s; s += good[j]; }
    gn[b] = s;
  }
  __syncthreads();
  if (k < TOPK && good[k]) {
    int r = pref[k];
    lx[b * TOPK + r] = slotx[b * TOPK + k];        // reference indexes ORIGINAL sorted coords
    ly[b * TOPK + r] = sloty[b * TOPK + k];
    llab[b * TOPK + r] = r + 1;
  }
}

// ---------------- K11: class histogram + emit final labels ----------------
__global__ __launch_bounds__(256) void k_hist(const int* __restrict__ lab,
    const uint8_t* __restrict__ segc, float* __restrict__ out_final,
    uint32_t* __restrict__ hist) {
  int b = blockIdx.y;
  __shared__ uint32_t sh[NSEG * NCC];
  for (int j = threadIdx.x; j < NSEG * NCC; j += 256) sh[j] = 0;
  __syncthreads();
  int chunk = NPIX / gridDim.x;
  int p0 = blockIdx.x * chunk;
  for (int p = p0 + threadIdx.x; p < p0 + chunk; p += 256) {
    size_t i = (size_t)b * NPIX + p;
    int l = lab[i];
    int c = (int)segc[i];
    out_final[i] = (float)l;
    atomicAdd(&sh[l * NCC + c], 1u);
  }
  __syncthreads();
  for (int j = threadIdx.x; j < NSEG * NCC; j += 256)
    if (sh[j]) atomicAdd(&hist[(size_t)b * NSEG * NCC + j], sh[j]);
}

// ---------------- K12: per-instance mode class + count ----------------
__global__ void k_mode(const uint32_t* __restrict__ hist, int* __restrict__ instc,
    float* __restrict__ out_instc, float* __restrict__ out_cntf) {
  int b = blockIdx.x;
  int j = threadIdx.x;
  if (j >= NSEG) return;
  const uint32_t* hr = hist + ((size_t)b * NSEG + j) * NCC;
  uint32_t bv = hr[0], s = hr[0]; int bc = 0;
  #pragma unroll
  for (int c = 1; c < NCC; ++c) {
    uint32_t v = hr[c]; s += v;
    if (v > bv) { bv = v; bc = c; }                // first-max tie-break
  }
  instc[b * NSEG + j] = bc;
  out_instc[b * NSEG + j] = (float)bc;
  out_cntf[b * NSEG + j] = (float)s;
}

// ---------------- K13: sum softmax prob of instance class per label ----------------
__global__ __launch_bounds__(256) void k_sg(const float* __restrict__ seg,
    const int* __restrict__ lab, const int* __restrict__ instc,
    const float* __restrict__ mbuf, const float* __restrict__ invs,
    long long* __restrict__ Ssel) {
  int b = blockIdx.y;
  __shared__ unsigned long long ss[NSEG];
  for (int j = threadIdx.x; j < NSEG; j += 256) ss[j] = 0;
  __syncthreads();
  int t = blockIdx.x * 256 + threadIdx.x;
  int p0 = t * 64;
  const int* lp = lab + (size_t)b * NPIX;
  const float* mb = mbuf + (size_t)b * NPIX;
  const float* iv = invs + (size_t)b * NPIX;
  const int* ic = instc + b * NSEG;
  int lA = -1, lB = -1; long long sA = 0, sB = 0;
  for (int q = 0; q < 64; ++q) {
    int p = p0 + q;
    int l = lp[p];
    int c = ic[l];
    float x = seg[((size_t)b * NCC + c) * NPIX + p];
    float pr = expf(x - mb[p]) * iv[p];
    long long qv = __double2ll_rn((double)pr * 4294967296.0);   // 2^32 fixed-point
    if (l == lA) sA += qv;
    else if (l == lB) sB += qv;
    else if (lA < 0) { lA = l; sA = qv; }
    else if (lB < 0) { lB = l; sB = qv; }
    else atomicAdd(&ss[l], (unsigned long long)qv);
  }
  if (lA >= 0) atomicAdd(&ss[lA], (unsigned long long)sA);
  if (lB >= 0) atomicAdd(&ss[lB], (unsigned long long)sB);
  __syncthreads();
  for (int j = threadIdx.x; j < NSEG; j += 256)
    if (ss[j]) atomicAdd((unsigned long long*)&Ssel[b * NSEG + j], ss[j]);
}

// ---------------- K14: seg_prob = Ssel / max(cntf,1) ----------------
__global__ void k_prob(const long long* __restrict__ Ssel,
    const float* __restrict__ out_cntf, float* __restrict__ out_prob) {
  int i = blockIdx.x * blockDim.x + threadIdx.x;
  if (i >= BB * NSEG) return;
  double s = (double)Ssel[i] * (1.0 / 4294967296.0);
  float c = out_cntf[i];
  out_prob[i] = (float)(s / (double)fmaxf(c, 1.0f));
}

extern "C" void kernel_launch(void* const* d_in, const int* in_sizes, int n_in,
                              void* d_out, int out_size, void* d_ws, size_t ws_size,
                              hipStream_t stream) {
  const float* seg = (const float*)d_in[0];
  const float* cr  = (const float*)d_in[2];
  float* out = (float*)d_out;

  float* out_final  = out;
  float* out_segmap = out + (size_t)BB * NPIX;
  float* out_instc  = out + (size_t)2 * BB * NPIX;
  float* out_prob   = out_instc + BB * NSEG;
  float* out_cntf   = out_prob + BB * NSEG;

  char* ws = (char*)d_ws;
  size_t off = 0;
  auto take = [&](size_t n) { size_t o = off; off += (n + 255) & ~(size_t)255; return o; };

  int32_t*  labA = (int32_t*)(ws + take((size_t)BB * NPIX * 4));  // vote -> lab0 -> final
  int32_t*  labB = (int32_t*)(ws + take((size_t)BB * NPIX * 4));  // lab1
  float*    mbuf = (float*)(ws + take((size_t)BB * NPIX * 4));
  float*    invs = (float*)(ws + take((size_t)BB * NPIX * 4));
  uint8_t*  segc = (uint8_t*)(ws + take((size_t)BB * NPIX));

  size_t zero_begin = off;
  uint32_t* cand_cnt = (uint32_t*)(ws + take(BB * 4));
  uint32_t* cand_val = (uint32_t*)(ws + take((size_t)BB * CAP * 4));
  uint32_t* cand_idx = (uint32_t*)(ws + take((size_t)BB * CAP * 4));
  float* slotx = (float*)(ws + take(BB * TOPK * 4));
  float* sloty = (float*)(ws + take(BB * TOPK * 4));
  int*   slotlab = (int*)(ws + take(BB * TOPK * 4));
  int*   n0 = (int*)(ws + take(BB * 4));
  float* l1x = (float*)(ws + take(BB * TOPK * 4));
  float* l1y = (float*)(ws + take(BB * TOPK * 4));
  int*   l1lab = (int*)(ws + take(BB * TOPK * 4));
  int*   n1 = (int*)(ws + take(BB * 4));
  float* l2x = (float*)(ws + take(BB * TOPK * 4));
  float* l2y = (float*)(ws + take(BB * TOPK * 4));
  int*   l2lab = (int*)(ws + take(BB * TOPK * 4));
  int*   n2 = (int*)(ws + take(BB * 4));
  uint32_t* cnt0 = (uint32_t*)(ws + take(BB * NSEG * 4));
  int* ymin = (int*)(ws + take(BB * NSEG * 4));
  int* ymax = (int*)(ws + take(BB * NSEG * 4));
  int* xmin = (int*)(ws + take(BB * NSEG * 4));
  int* xmax = (int*)(ws + take(BB * NSEG * 4));
  uint32_t* cnt2 = (uint32_t*)(ws + take(BB * NSEG * 4));
  long long* sxq = (long long*)(ws + take(BB * NSEG * 8));
  long long* syq = (long long*)(ws + take(BB * NSEG * 8));
  uint32_t* hist = (uint32_t*)(ws + take((size_t)BB * NSEG * NCC * 4));
  int* instc = (int*)(ws + take(BB * NSEG * 4));
  long long* Ssel = (long long*)(ws + take(BB * NSEG * 8));
  size_t zero_end = off;

  if (ws_size < off) return;  // workspace too small -> fail visibly

  hipMemsetAsync(labA, 0, (size_t)BB * NPIX * 4, stream);              // vote counts
  hipMemsetAsync(ws + zero_begin, 0, zero_end - zero_begin, stream);   // all small accumulators
  k_init_minmax<<<(BB * NSEG + 255) / 256, 256, 0, stream>>>(ymin, ymax, xmin, xmax);

  k_pixel<<<BB * NPIX / 256, 256, 0, stream>>>(seg, cr, out_segmap,
      (uint32_t*)labA, mbuf, invs, segc);
  k_nms<<<BB * NPIX / 256, 256, 0, stream>>>((const uint32_t*)labA,
      cand_cnt, cand_val, cand_idx);
  k_topk<<<BB, 256, 0, stream>>>(cand_cnt, cand_val, cand_idx, slotx, sloty, slotlab, n0);

  dim3 agrid(NPIX / 256, BB);
  dim3 sgrid(NPIX / 64 / 256, BB);   // (32, B)

  // pass 0: all top-k candidates, fallback 0
  k_assign<<<agrid, 256, 0, stream>>>(cr, segc, slotx, sloty, slotlab, n0, (const int*)nullptr, labA);
  k_stats1<<<sgrid, 256, 0, stream>>>(labA, cnt0, ymin, ymax, xmin, xmax);
  k_build1<<<BB, 256, 0, stream>>>(cnt0, ymin, ymax, xmin, xmax, slotx, sloty, l1x, l1y, l1lab, n1);
  // pass 1: ratio-pruned compact list, fallback lab0
  k_assign<<<agrid, 256, 0, stream>>>(cr, segc, l1x, l1y, l1lab, n1, labA, labB);
  k_stats2<<<sgrid, 256, 0, stream>>>(labB, cr, cnt2, sxq, syq);
  k_build2<<<BB, 256, 0, stream>>>(cnt2, sxq, syq, slotx, sloty, l2x, l2y, l2lab, n2);
  // pass 2: mean-pruned compact list, fallback lab1 -> final into labA
  k_assign<<<agrid, 256, 0, stream>>>(cr, segc, l2x, l2y, l2lab, n2, labB, labA);

  k_hist<<<dim3(64, BB), 256, 0, stream>>>(labA, segc, out_final, hist);
  k_mode<<<BB, 256, 0, stream>>>(hist, instc, out_instc, out_cntf);
  k_sg<<<sgrid, 256, 0, stream>>>(seg, labA, instc, mbuf, invs, Ssel);
  k_prob<<<(BB * NSEG + 255) / 256, 256, 0, stream>>>(Ssel, out_cntf, out_prob);
}

// Round 2
// 172.599 us; speedup vs baseline: 1.8420x; 1.8420x over previous
//
#include <hip/hip_runtime.h>
#include <stdint.h>

#define HH   512
#define WW   1024
#define BB   2
#define NCC  34
#define PADK 7
#define TOPK 200
#define NSEG (TOPK + 1)
#define WPAD (WW + 2 * PADK)   // 1038
#define NPIX (HH * WW)         // 524288
#define CAP  12288
#define INTMAXC  0x7FFFFFFF
#define INTMINC  (-0x7FFFFFFF - 1)

// ---------------- K0: init min/max stat arrays ----------------
__global__ void k_init_minmax(int* __restrict__ y0, int* __restrict__ y1,
                              int* __restrict__ x0, int* __restrict__ x1) {
  int i = blockIdx.x * blockDim.x + threadIdx.x;
  if (i < BB * NSEG) { y0[i] = INTMAXC; y1[i] = INTMINC; x0[i] = INTMAXC; x1[i] = INTMINC; }
}

// ---------------- K1: per-pixel fused pass (4 px/thread, online softmax) ----------------
__global__ __launch_bounds__(256) void k_pixel(const float* __restrict__ seg,
    const float* __restrict__ cr, float* __restrict__ out_segmap,
    uint32_t* __restrict__ vote, float* __restrict__ mbuf,
    float* __restrict__ invs, uint8_t* __restrict__ segc) {
  int t = blockIdx.x * 256 + threadIdx.x;          // [0, BB*NPIX/4)
  int b = t >> 17;                                 // NPIX/4 = 131072 = 2^17
  int p = (t & 131071) << 2;
  int h = p >> 10, w = p & 1023;
  size_t i = (size_t)b * NPIX + p;
  const float* base = seg + (size_t)b * NCC * NPIX + p;

  float4 m = *reinterpret_cast<const float4*>(base);
  float4 s = make_float4(1.f, 1.f, 1.f, 1.f);
  int4 am = make_int4(0, 0, 0, 0);
  for (int c = 1; c < NCC; ++c) {
    float4 x = *reinterpret_cast<const float4*>(base + (size_t)c * NPIX);
    // branchless online softmax: exp(0)==1 exactly, so result == two-pass sum
    { float mn = fmaxf(m.x, x.x); s.x = s.x * expf(m.x - mn) + expf(x.x - mn); if (x.x > m.x) am.x = c; m.x = mn; }
    { float mn = fmaxf(m.y, x.y); s.y = s.y * expf(m.y - mn) + expf(x.y - mn); if (x.y > m.y) am.y = c; m.y = mn; }
    { float mn = fmaxf(m.z, x.z); s.z = s.z * expf(m.z - mn) + expf(x.z - mn); if (x.z > m.z) am.z = c; m.z = mn; }
    { float mn = fmaxf(m.w, x.w); s.w = s.w * expf(m.w - mn) + expf(x.w - mn); if (x.w > m.w) am.w = c; m.w = mn; }
  }
  *reinterpret_cast<float4*>(out_segmap + i) =
      make_float4((float)am.x, (float)am.y, (float)am.z, (float)am.w);
  *reinterpret_cast<uchar4*>(segc + i) =
      make_uchar4((unsigned char)am.x, (unsigned char)am.y, (unsigned char)am.z, (unsigned char)am.w);
  *reinterpret_cast<float4*>(mbuf + i) = m;
  *reinterpret_cast<float4*>(invs + i) = make_float4(1.f / s.x, 1.f / s.y, 1.f / s.z, 1.f / s.w);

  // ---- vote targets ----
  const float* c0 = cr + (size_t)b * 2 * NPIX + p;
  float4 r0 = *reinterpret_cast<const float4*>(c0);
  float4 r1 = *reinterpret_cast<const float4*>(c0 + NPIX);
  float crx[4] = {r0.x, r0.y, r0.z, r0.w};
  float cry[4] = {r1.x, r1.y, r1.z, r1.w};
  int amA[4] = {am.x, am.y, am.z, am.w};
  int tgt[4];
  #pragma unroll
  for (int q = 0; q < 4; ++q) {
    tgt[q] = -1;
    if (amA[q] >= 24) {                            // "things": class in (23.99, 33]
      float ccx = (float)(w + q + 1) - crx[q];
      float ccy = (float)(h + 1) - cry[q];
      float rx = rintf(ccx), ry = rintf(ccy);      // matches jnp.round (half-to-even)
      if (rx >= 0.f && ry >= 0.f && rx < (float)WW && ry < (float)HH)
        tgt[q] = (int)ry * WW + (int)rx;
    }
  }
  // ---- wave-aggregated vote atomics (targets highly redundant within wave) ----
  int lane = threadIdx.x & 63;
  uint32_t* vb = vote + (size_t)b * NPIX;
  #pragma unroll
  for (int q = 0; q < 4; ++q) {
    int tq = tgt[q];
    unsigned long long act = __ballot(tq >= 0);
    while (act) {
      int leader = __ffsll(act) - 1;
      int tl = __shfl(tq, leader);
      unsigned long long mt = __ballot(tq == tl);
      if (lane == leader) atomicAdd(&vb[tl], (uint32_t)__popcll(mt & act));
      act &= ~mt;
    }
  }
}

// ---------------- K2: 7x7 NMS, collect candidates ----------------
__global__ __launch_bounds__(256) void k_nms(const uint32_t* __restrict__ vote,
    uint32_t* __restrict__ cand_cnt, uint32_t* __restrict__ cand_val,
    uint32_t* __restrict__ cand_idx) {
  int i = blockIdx.x * 256 + threadIdx.x;
  int b = i / NPIX, p = i - b * NPIX;
  int h = p / WW, w = p - h * WW;
  uint32_t v = vote[i];
  if (v <= 50u) return;                            // nms > 50.0 <=> count >= 51
  const uint32_t* vb = vote + (size_t)b * NPIX;
  for (int dy = -3; dy <= 3; ++dy) {
    int yy = h + dy; if (yy < 0 || yy >= HH) continue;
    for (int dx = -3; dx <= 3; ++dx) {
      int xx = w + dx; if (xx < 0 || xx >= WW) continue;
      if (vb[yy * WW + xx] > v) return;            // strictly-greater disqualifies (ties kept)
    }
  }
  uint32_t pos = atomicAdd(&cand_cnt[b], 1u);
  if (pos < CAP) {
    cand_val[b * CAP + pos] = v;
    cand_idx[b * CAP + pos] = (uint32_t)((h + PADK) * WPAD + (w + PADK));  // PADDED coords
  }
}

// ---------------- K3: top-200 select with lax.top_k tie order ----------------
__global__ void k_topk(const uint32_t* __restrict__ cand_cnt,
    const uint32_t* __restrict__ cand_val, const uint32_t* __restrict__ cand_idx,
    float* __restrict__ slotx, float* __restrict__ sloty, int* __restrict__ gn0) {
  int b = blockIdx.x;
  int n = (int)cand_cnt[b]; if (n > CAP) n = CAP;
  const uint32_t* cv = cand_val + b * CAP;
  const uint32_t* ci = cand_idx + b * CAP;
  for (int i = threadIdx.x; i < n; i += blockDim.x) {
    unsigned long long ki = ((unsigned long long)cv[i] << 20) | (unsigned long long)(0xFFFFFu - ci[i]);
    int r = 0;
    for (int j = 0; j < n; ++j) {
      unsigned long long kj = ((unsigned long long)cv[j] << 20) | (unsigned long long)(0xFFFFFu - ci[j]);
      r += (kj > ki) ? 1 : 0;                      // value desc, index asc (keys unique)
    }
    if (r < TOPK) {
      uint32_t idx = ci[i];
      slotx[b * TOPK + r] = (float)(idx % WPAD);   // cx = ti % Wp
      sloty[b * TOPK + r] = (float)(idx / WPAD);   // cy = ti // Wp
    }
  }
  if (threadIdx.x == 0) gn0[b] = (n < TOPK) ? n : TOPK;
}

// label of center k (0-based, compacted ascending-slot list) is always k+1.
// 4 px/thread; distance with explicit rn mul/add (no FMA) to bit-match numpy.
__device__ __forceinline__ void assign4(int n, const float* sxs, const float* sys,
    const uchar4 sc4, const float4 r0, const float4 r1, int h, int w, int* l) {
  float ccx[4], ccy[4], bd[4];
  int bi[4];
  float crx[4] = {r0.x, r0.y, r0.z, r0.w};
  float cry[4] = {r1.x, r1.y, r1.z, r1.w};
  #pragma unroll
  for (int q = 0; q < 4; ++q) {
    ccx[q] = (float)(w + q + 1) - crx[q];
    ccy[q] = (float)(h + 1) - cry[q];
    bd[q] = 3.4e38f; bi[q] = 0;
  }
  for (int k = 0; k < n; ++k) {
    float cxk = sxs[k], cyk = sys[k];
    #pragma unroll
    for (int q = 0; q < 4; ++q) {
      float dx = ccx[q] - cxk, dy = ccy[q] - cyk;
      float d = __fadd_rn(__fmul_rn(dx, dx), __fmul_rn(dy, dy));
      if (d < bd[q]) { bd[q] = d; bi[q] = k; }     // strict <: earliest slot wins ties
    }
  }
  unsigned char cls[4] = {sc4.x, sc4.y, sc4.z, sc4.w};
  #pragma unroll
  for (int q = 0; q < 4; ++q) l[q] = (cls[q] >= 24) ? bi[q] + 1 : 0;
}

// ---------------- K4: assign pass0 + count/bbox stats (one row per block) ----------------
__global__ __launch_bounds__(256) void k_assign0(const float* __restrict__ cr,
    const uint8_t* __restrict__ segc, const float* __restrict__ cx,
    const float* __restrict__ cy, const int* __restrict__ ncent,
    int* __restrict__ outlab, uint32_t* __restrict__ gcnt,
    int* __restrict__ gy0, int* __restrict__ gy1,
    int* __restrict__ gx0, int* __restrict__ gx1) {
  int b = blockIdx.y;
  int h = blockIdx.x;                              // block == one row
  __shared__ float sxs[TOPK], sys[TOPK];
  __shared__ uint32_t sc[NSEG];
  __shared__ int sx0[NSEG], sx1[NSEG];
  int n = ncent[b];
  for (int k = threadIdx.x; k < n; k += 256) { sxs[k] = cx[b * TOPK + k]; sys[k] = cy[b * TOPK + k]; }
  for (int j = threadIdx.x; j < NSEG; j += 256) { sc[j] = 0; sx0[j] = INTMAXC; sx1[j] = INTMINC; }
  __syncthreads();
  int w = threadIdx.x * 4;
  size_t i = (size_t)b * NPIX + h * WW + w;
  const float* c0 = cr + (size_t)b * 2 * NPIX + h * WW + w;
  uchar4 sc4 = *reinterpret_cast<const uchar4*>(segc + i);
  float4 r0 = *reinterpret_cast<const float4*>(c0);
  float4 r1 = *reinterpret_cast<const float4*>(c0 + NPIX);
  int l[4];
  if (n == 0) { l[0] = l[1] = l[2] = l[3] = 0; }   // any_c false -> lab0 = 0
  else assign4(n, sxs, sys, sc4, r0, r1, h, w, l);
  *reinterpret_cast<int4*>(outlab + i) = make_int4(l[0], l[1], l[2], l[3]);
  // per-thread run merge -> shared atomics (label-0 stats unused by g1)
  int cur = -1; uint32_t rc = 0; int rx0 = 0, rx1 = 0;
  #pragma unroll
  for (int q = 0; q < 4; ++q) {
    int lq = l[q], x = w + q;
    if (lq == cur) { rc++; rx1 = x; }
    else {
      if (cur > 0) { atomicAdd(&sc[cur], rc); atomicMin(&sx0[cur], rx0); atomicMax(&sx1[cur], rx1); }
      cur = lq; rc = 1; rx0 = rx1 = x;
    }
  }
  if (cur > 0) { atomicAdd(&sc[cur], rc); atomicMin(&sx0[cur], rx0); atomicMax(&sx1[cur], rx1); }
  __syncthreads();
  for (int j = threadIdx.x; j < NSEG; j += 256) {
    if (sc[j]) {
      atomicAdd(&gcnt[b * NSEG + j], sc[j]);
      atomicMin(&gy0[b * NSEG + j], h); atomicMax(&gy1[b * NSEG + j], h);
      atomicMin(&gx0[b * NSEG + j], sx0[j]); atomicMax(&gx1[b * NSEG + j], sx1[j]);
    }
  }
}

// ---------------- K6: bbox-ratio pruning -> compact list 1 ----------------
__global__ void k_build1(const uint32_t* __restrict__ gcnt, const int* __restrict__ gy0,
    const int* __restrict__ gy1, const int* __restrict__ gx0, const int* __restrict__ gx1,
    const float* __restrict__ slotx, const float* __restrict__ sloty,
    float* __restrict__ lx, float* __restrict__ ly, int* __restrict__ gn) {
  int b = blockIdx.x;
  __shared__ int good[TOPK];
  __shared__ int pref[TOPK];
  int k = threadIdx.x;
  if (k < TOPK) {
    uint32_t c = gcnt[b * NSEG + k + 1];
    int g = 0;
    if (c > 0) {
      int j = b * NSEG + k + 1;
      float area = (float)((gy1[j] - gy0[j] + 1) * (gx1[j] - gx0[j] + 1));  // exact (< 2^24)
      float ratio = (float)c / area;               // same IEEE div as reference
      g = (ratio > 0.3f) ? 1 : 0;
    }
    good[k] = g;
  }
  __syncthreads();
  if (threadIdx.x == 0) {
    int s = 0;
    for (int j = 0; j < TOPK; ++j) { pref[j] = s; s += good[j]; }
    gn[b] = s;
  }
  __syncthreads();
  if (k < TOPK && good[k]) {
    int r = pref[k];
    lx[b * TOPK + r] = slotx[b * TOPK + k];
    ly[b * TOPK + r] = sloty[b * TOPK + k];
  }
}

// ---------------- K7: assign pass1 + count/fixed-point cr sums ----------------
__global__ __launch_bounds__(256) void k_assign1(const float* __restrict__ cr,
    const uint8_t* __restrict__ segc, const float* __restrict__ cx,
    const float* __restrict__ cy, const int* __restrict__ ncent,
    const int* __restrict__ fb, int* __restrict__ outlab,
    uint32_t* __restrict__ gcnt, long long* __restrict__ gsx, long long* __restrict__ gsy) {
  int b = blockIdx.y;
  int h = blockIdx.x;
  __shared__ float sxs[TOPK], sys[TOPK];
  __shared__ uint32_t sc[NSEG];
  __shared__ unsigned long long ssx[NSEG], ssy[NSEG];
  int n = ncent[b];
  for (int k = threadIdx.x; k < n; k += 256) { sxs[k] = cx[b * TOPK + k]; sys[k] = cy[b * TOPK + k]; }
  for (int j = threadIdx.x; j < NSEG; j += 256) { sc[j] = 0; ssx[j] = 0; ssy[j] = 0; }
  __syncthreads();
  int w = threadIdx.x * 4;
  size_t i = (size_t)b * NPIX + h * WW + w;
  const float* c0 = cr + (size_t)b * 2 * NPIX + h * WW + w;
  uchar4 sc4 = *reinterpret_cast<const uchar4*>(segc + i);
  float4 r0 = *reinterpret_cast<const float4*>(c0);
  float4 r1 = *reinterpret_cast<const float4*>(c0 + NPIX);
  int l[4];
  if (n == 0) { int4 f = *reinterpret_cast<const int4*>(fb + i); l[0]=f.x; l[1]=f.y; l[2]=f.z; l[3]=f.w; }
  else assign4(n, sxs, sys, sc4, r0, r1, h, w, l);
  *reinterpret_cast<int4*>(outlab + i) = make_int4(l[0], l[1], l[2], l[3]);
  float crx[4] = {r0.x, r0.y, r0.z, r0.w};
  float cry[4] = {r1.x, r1.y, r1.z, r1.w};
  int cur = -1; uint32_t rc = 0; long long ax = 0, ay = 0;
  #pragma unroll
  for (int q = 0; q < 4; ++q) {
    int lq = l[q];
    long long qx = __double2ll_rn((double)crx[q] * 1048576.0);   // 2^20 fixed-point
    long long qy = __double2ll_rn((double)cry[q] * 1048576.0);
    if (lq == cur) { rc++; ax += qx; ay += qy; }
    else {
      if (cur > 0) { atomicAdd(&sc[cur], rc);
                     atomicAdd(&ssx[cur], (unsigned long long)ax);
                     atomicAdd(&ssy[cur], (unsigned long long)ay); }
      cur = lq; rc = 1; ax = qx; ay = qy;
    }
  }
  if (cur > 0) { atomicAdd(&sc[cur], rc);
                 atomicAdd(&ssx[cur], (unsigned long long)ax);
                 atomicAdd(&ssy[cur], (unsigned long long)ay); }
  __syncthreads();
  for (int j = threadIdx.x; j < NSEG; j += 256) {
    if (sc[j]) {
      atomicAdd(&gcnt[b * NSEG + j], sc[j]);
      atomicAdd((unsigned long long*)&gsx[b * NSEG + j], ssx[j]);
      atomicAdd((unsigned long long*)&gsy[b * NSEG + j], ssy[j]);
    }
  }
}

// ---------------- K9: mean pruning -> compact list 2 (ORIGINAL slot coords) ----------------
__global__ void k_build2(const uint32_t* __restrict__ gcnt, const long long* __restrict__ gsx,
    const long long* __restrict__ gsy, const float* __restrict__ slotx,
    const float* __restrict__ sloty, float* __restrict__ lx, float* __restrict__ ly,
    int* __restrict__ gn) {
  int b = blockIdx.x;
  __shared__ int good[TOPK];
  __shared__ int pref[TOPK];
  int k = threadIdx.x;
  if (k < TOPK) {
    uint32_t c = gcnt[b * NSEG + k + 1];           // stats are in COMPACT label space
    int g = 0;
    if (c > 0) {
      double inv = 1.0 / (double)c;
      double mx = ((double)gsx[b * NSEG + k + 1] * (1.0 / 1048576.0)) * inv;
      double my = ((double)gsy[b * NSEG + k + 1] * (1.0 / 1048576.0)) * inv;
      g = (fabs(mx) < 10.0 && fabs(my) < 10.0) ? 1 : 0;
    }
    good[k] = g;
  }
  __syncthreads();
  if (threadIdx.x == 0) {
    int s = 0;
    for (int j = 0; j < TOPK; ++j) { pref[j] = s; s += good[j]; }
    gn[b] = s;
  }
  __syncthreads();
  if (k < TOPK && good[k]) {
    int r = pref[k];
    lx[b * TOPK + r] = slotx[b * TOPK + k];        // reference indexes ORIGINAL sorted coords
    ly[b * TOPK + r] = sloty[b * TOPK + k];
  }
}

// ---------------- K10: assign pass2 + final write + class histogram ----------------
__global__ __launch_bounds__(256) void k_assign2(const float* __restrict__ cr,
    const uint8_t* __restrict__ segc, const float* __restrict__ cx,
    const float* __restrict__ cy, const int* __restrict__ ncent,
    const int* __restrict__ fb, int* __restrict__ outlab,
    float* __restrict__ out_final, uint32_t* __restrict__ hist) {
  int b = blockIdx.y;
  __shared__ float sxs[TOPK], sys[TOPK];
  __shared__ uint32_t sh[NSEG * NCC];
  int n = ncent[b];
  for (int k = threadIdx.x; k < n; k += 256) { sxs[k] = cx[b * TOPK + k]; sys[k] = cy[b * TOPK + k]; }
  for (int j = threadIdx.x; j < NSEG * NCC; j += 256) sh[j] = 0;
  __syncthreads();
  for (int it = 0; it < 4; ++it) {                 // 128 blocks/batch x 4096 px
    int p = blockIdx.x * 4096 + it * 1024 + threadIdx.x * 4;
    int h = p >> 10, w = p & 1023;
    size_t i = (size_t)b * NPIX + p;
    const float* c0 = cr + (size_t)b * 2 * NPIX + p;
    uchar4 sc4 = *reinterpret_cast<const uchar4*>(segc + i);
    float4 r0 = *reinterpret_cast<const float4*>(c0);
    float4 r1 = *reinterpret_cast<const float4*>(c0 + NPIX);
    int l[4];
    if (n == 0) { int4 f = *reinterpret_cast<const int4*>(fb + i); l[0]=f.x; l[1]=f.y; l[2]=f.z; l[3]=f.w; }
    else assign4(n, sxs, sys, sc4, r0, r1, h, w, l);
    *reinterpret_cast<int4*>(outlab + i) = make_int4(l[0], l[1], l[2], l[3]);
    *reinterpret_cast<float4*>(out_final + i) =
        make_float4((float)l[0], (float)l[1], (float)l[2], (float)l[3]);
    unsigned char cls[4] = {sc4.x, sc4.y, sc4.z, sc4.w};
    #pragma unroll
    for (int q = 0; q < 4; ++q) atomicAdd(&sh[l[q] * NCC + cls[q]], 1u);
  }
  __syncthreads();
  for (int j = threadIdx.x; j < NSEG * NCC; j += 256)
    if (sh[j]) atomicAdd(&hist[(size_t)b * NSEG * NCC + j], sh[j]);
}

// ---------------- K12: per-instance mode class + count ----------------
__global__ void k_mode(const uint32_t* __restrict__ hist, int* __restrict__ instc,
    float* __restrict__ out_instc, float* __restrict__ out_cntf) {
  int b = blockIdx.x;
  int j = threadIdx.x;
  if (j >= NSEG) return;
  const uint32_t* hr = hist + ((size_t)b * NSEG + j) * NCC;
  uint32_t bv = hr[0], s = hr[0]; int bc = 0;
  #pragma unroll
  for (int c = 1; c < NCC; ++c) {
    uint32_t v = hr[c]; s += v;
    if (v > bv) { bv = v; bc = c; }                // first-max tie-break
  }
  instc[b * NSEG + j] = bc;
  out_instc[b * NSEG + j] = (float)bc;
  out_cntf[b * NSEG + j] = (float)s;
}

// ---------------- K13: sum softmax prob of instance class per label ----------------
__global__ __launch_bounds__(256) void k_sg(const float* __restrict__ seg,
    const int* __restrict__ lab, const int* __restrict__ instc,
    const float* __restrict__ mbuf, const float* __restrict__ invs,
    long long* __restrict__ Ssel) {
  int b = blockIdx.y;
  __shared__ unsigned long long ss[NSEG];
  __shared__ int icS[NSEG];
  for (int j = threadIdx.x; j < NSEG; j += 256) { ss[j] = 0; icS[j] = instc[b * NSEG + j]; }
  __syncthreads();
  int p = (blockIdx.x * 256 + threadIdx.x) * 4;
  size_t i = (size_t)b * NPIX + p;
  int4 l4 = *reinterpret_cast<const int4*>(lab + i);
  float4 mb = *reinterpret_cast<const float4*>(mbuf + i);
  float4 iv = *reinterpret_cast<const float4*>(invs + i);
  const float* sb = seg + (size_t)b * NCC * NPIX + p;
  int lA[4] = {l4.x, l4.y, l4.z, l4.w};
  float mbA[4] = {mb.x, mb.y, mb.z, mb.w};
  float ivA[4] = {iv.x, iv.y, iv.z, iv.w};
  int cur = -1; long long acc = 0;                 // label 0 IS included here
  #pragma unroll
  for (int q = 0; q < 4; ++q) {
    int lq = lA[q];
    int c = icS[lq];
    float x = sb[(size_t)c * NPIX + q];
    float pr = expf(x - mbA[q]) * ivA[q];
    long long qv = __double2ll_rn((double)pr * 4294967296.0);   // 2^32 fixed-point
    if (lq == cur) acc += qv;
    else { if (cur >= 0) atomicAdd(&ss[cur], (unsigned long long)acc); cur = lq; acc = qv; }
  }
  if (cur >= 0) atomicAdd(&ss[cur], (unsigned long long)acc);
  __syncthreads();
  for (int j = threadIdx.x; j < NSEG; j += 256)
    if (ss[j]) atomicAdd((unsigned long long*)&Ssel[b * NSEG + j], ss[j]);
}

// ---------------- K14: seg_prob = Ssel / max(cntf,1) ----------------
__global__ void k_prob(const long long* __restrict__ Ssel,
    const float* __restrict__ out_cntf, float* __restrict__ out_prob) {
  int i = blockIdx.x * blockDim.x + threadIdx.x;
  if (i >= BB * NSEG) return;
  double s = (double)Ssel[i] * (1.0 / 4294967296.0);
  float c = out_cntf[i];
  out_prob[i] = (float)(s / (double)fmaxf(c, 1.0f));
}

extern "C" void kernel_launch(void* const* d_in, const int* in_sizes, int n_in,
                              void* d_out, int out_size, void* d_ws, size_t ws_size,
                              hipStream_t stream) {
  const float* seg = (const float*)d_in[0];
  const float* cr  = (const float*)d_in[2];
  float* out = (float*)d_out;

  float* out_final  = out;
  float* out_segmap = out + (size_t)BB * NPIX;
  float* out_instc  = out + (size_t)2 * BB * NPIX;
  float* out_prob   = out_instc + BB * NSEG;
  float* out_cntf   = out_prob + BB * NSEG;

  char* ws = (char*)d_ws;
  size_t off = 0;
  auto take = [&](size_t n) { size_t o = off; off += (n + 255) & ~(size_t)255; return o; };

  int32_t*  labA = (int32_t*)(ws + take((size_t)BB * NPIX * 4));  // vote -> lab0 -> final
  int32_t*  labB = (int32_t*)(ws + take((size_t)BB * NPIX * 4));  // lab1
  float*    mbuf = (float*)(ws + take((size_t)BB * NPIX * 4));
  float*    invs = (float*)(ws + take((size_t)BB * NPIX * 4));
  uint8_t*  segc = (uint8_t*)(ws + take((size_t)BB * NPIX));

  size_t zero_begin = off;
  uint32_t* cand_cnt = (uint32_t*)(ws + take(BB * 4));
  uint32_t* cand_val = (uint32_t*)(ws + take((size_t)BB * CAP * 4));
  uint32_t* cand_idx = (uint32_t*)(ws + take((size_t)BB * CAP * 4));
  float* slotx = (float*)(ws + take(BB * TOPK * 4));
  float* sloty = (float*)(ws + take(BB * TOPK * 4));
  int*   n0 = (int*)(ws + take(BB * 4));
  float* l1x = (float*)(ws + take(BB * TOPK * 4));
  float* l1y = (float*)(ws + take(BB * TOPK * 4));
  int*   n1 = (int*)(ws + take(BB * 4));
  float* l2x = (float*)(ws + take(BB * TOPK * 4));
  float* l2y = (float*)(ws + take(BB * TOPK * 4));
  int*   n2 = (int*)(ws + take(BB * 4));
  uint32_t* cnt0 = (uint32_t*)(ws + take(BB * NSEG * 4));
  int* ymin = (int*)(ws + take(BB * NSEG * 4));
  int* ymax = (int*)(ws + take(BB * NSEG * 4));
  int* xmin = (int*)(ws + take(BB * NSEG * 4));
  int* xmax = (int*)(ws + take(BB * NSEG * 4));
  uint32_t* cnt2 = (uint32_t*)(ws + take(BB * NSEG * 4));
  long long* sxq = (long long*)(ws + take(BB * NSEG * 8));
  long long* syq = (long long*)(ws + take(BB * NSEG * 8));
  uint32_t* hist = (uint32_t*)(ws + take((size_t)BB * NSEG * NCC * 4));
  int* instc = (int*)(ws + take(BB * NSEG * 4));
  long long* Ssel = (long long*)(ws + take(BB * NSEG * 8));
  size_t zero_end = off;

  if (ws_size < off) return;  // workspace too small -> fail visibly

  hipMemsetAsync(labA, 0, (size_t)BB * NPIX * 4, stream);              // vote counts
  hipMemsetAsync(ws + zero_begin, 0, zero_end - zero_begin, stream);   // small accumulators
  k_init_minmax<<<(BB * NSEG + 255) / 256, 256, 0, stream>>>(ymin, ymax, xmin, xmax);

  k_pixel<<<BB * NPIX / 4 / 256, 256, 0, stream>>>(seg, cr, out_segmap,
      (uint32_t*)labA, mbuf, invs, segc);
  k_nms<<<BB * NPIX / 256, 256, 0, stream>>>((const uint32_t*)labA,
      cand_cnt, cand_val, cand_idx);
  k_topk<<<BB, 256, 0, stream>>>(cand_cnt, cand_val, cand_idx, slotx, sloty, n0);

  dim3 rgrid(HH, BB);                              // one row per block

  // pass 0: all top-k candidates (fallback 0) + cnt/bbox stats
  k_assign0<<<rgrid, 256, 0, stream>>>(cr, segc, slotx, sloty, n0, labA,
      cnt0, ymin, ymax, xmin, xmax);
  k_build1<<<BB, 256, 0, stream>>>(cnt0, ymin, ymax, xmin, xmax, slotx, sloty, l1x, l1y, n1);
  // pass 1: ratio-pruned compact list (fallback lab0) + cnt/cr-sum stats
  k_assign1<<<rgrid, 256, 0, stream>>>(cr, segc, l1x, l1y, n1, labA, labB, cnt2, sxq, syq);
  k_build2<<<BB, 256, 0, stream>>>(cnt2, sxq, syq, slotx, sloty, l2x, l2y, n2);
  // pass 2: mean-pruned compact list (fallback lab1) + final write + histogram
  k_assign2<<<dim3(128, BB), 256, 0, stream>>>(cr, segc, l2x, l2y, n2, labB, labA,
      out_final, hist);

  k_mode<<<BB, 256, 0, stream>>>(hist, instc, out_instc, out_cntf);
  k_sg<<<dim3(NPIX / 1024, BB), 256, 0, stream>>>(seg, labA, instc, mbuf, invs, Ssel);
  k_prob<<<(BB * NSEG + 255) / 256, 256, 0, stream>>>(Ssel, out_cntf, out_prob);
}

// Round 3
// 169.047 us; speedup vs baseline: 1.8807x; 1.0210x over previous
//
#include <hip/hip_runtime.h>
#include <stdint.h>

#define HH   512
#define WW   1024
#define BB   2
#define NCC  34
#define PADK 7
#define TOPK 200
#define NSEG (TOPK + 1)
#define WPAD (WW + 2 * PADK)   // 1038
#define NPIX (HH * WW)         // 524288
#define CAP  12288
#define INTMAXC  0x7FFFFFFF
#define INTMINC  (-0x7FFFFFFF - 1)

// ---------------- K0: clear votes + accumulators, init min/max ----------------
// Replaces hipMemsetAsync (whose fillBufferAligned dispatches ran ~80us each
// at 10% occupancy) with one properly-sized kernel.
__global__ __launch_bounds__(256) void k_clear(uint4* __restrict__ votes,
    uint4* __restrict__ small, int nsm, int* __restrict__ y0, int* __restrict__ y1,
    int* __restrict__ x0, int* __restrict__ x1) {
  int t = blockIdx.x * 256 + threadIdx.x;
  if (t < BB * NPIX / 4) votes[t] = make_uint4(0u, 0u, 0u, 0u);
  if (t < nsm) small[t] = make_uint4(0u, 0u, 0u, 0u);
  if (t < BB * NSEG) { y0[t] = INTMAXC; y1[t] = INTMINC; x0[t] = INTMAXC; x1[t] = INTMINC; }
}

// ---------------- K1: per-pixel fused pass (4 px/thread, online softmax) ----------------
__global__ __launch_bounds__(256) void k_pixel(const float* __restrict__ seg,
    const float* __restrict__ cr, float* __restrict__ out_segmap,
    uint32_t* __restrict__ vote, float* __restrict__ mbuf,
    float* __restrict__ invs, uint8_t* __restrict__ segc) {
  int t = blockIdx.x * 256 + threadIdx.x;          // [0, BB*NPIX/4)
  int b = t >> 17;                                 // NPIX/4 = 131072 = 2^17
  int p = (t & 131071) << 2;
  int h = p >> 10, w = p & 1023;
  size_t i = (size_t)b * NPIX + p;
  const float* base = seg + (size_t)b * NCC * NPIX + p;

  float4 m = *reinterpret_cast<const float4*>(base);
  float4 s = make_float4(1.f, 1.f, 1.f, 1.f);
  int4 am = make_int4(0, 0, 0, 0);
  for (int c = 1; c < NCC; ++c) {
    float4 x = *reinterpret_cast<const float4*>(base + (size_t)c * NPIX);
    // branchless online softmax: exp(0)==1 exactly, so result == two-pass sum
    { float mn = fmaxf(m.x, x.x); s.x = s.x * expf(m.x - mn) + expf(x.x - mn); if (x.x > m.x) am.x = c; m.x = mn; }
    { float mn = fmaxf(m.y, x.y); s.y = s.y * expf(m.y - mn) + expf(x.y - mn); if (x.y > m.y) am.y = c; m.y = mn; }
    { float mn = fmaxf(m.z, x.z); s.z = s.z * expf(m.z - mn) + expf(x.z - mn); if (x.z > m.z) am.z = c; m.z = mn; }
    { float mn = fmaxf(m.w, x.w); s.w = s.w * expf(m.w - mn) + expf(x.w - mn); if (x.w > m.w) am.w = c; m.w = mn; }
  }
  *reinterpret_cast<float4*>(out_segmap + i) =
      make_float4((float)am.x, (float)am.y, (float)am.z, (float)am.w);
  *reinterpret_cast<uchar4*>(segc + i) =
      make_uchar4((unsigned char)am.x, (unsigned char)am.y, (unsigned char)am.z, (unsigned char)am.w);
  *reinterpret_cast<float4*>(mbuf + i) = m;
  *reinterpret_cast<float4*>(invs + i) = make_float4(1.f / s.x, 1.f / s.y, 1.f / s.z, 1.f / s.w);

  // ---- vote targets ----
  const float* c0 = cr + (size_t)b * 2 * NPIX + p;
  float4 r0 = *reinterpret_cast<const float4*>(c0);
  float4 r1 = *reinterpret_cast<const float4*>(c0 + NPIX);
  float crx[4] = {r0.x, r0.y, r0.z, r0.w};
  float cry[4] = {r1.x, r1.y, r1.z, r1.w};
  int amA[4] = {am.x, am.y, am.z, am.w};
  int tgt[4];
  #pragma unroll
  for (int q = 0; q < 4; ++q) {
    tgt[q] = -1;
    if (amA[q] >= 24) {                            // "things": class in (23.99, 33]
      float ccx = (float)(w + q + 1) - crx[q];
      float ccy = (float)(h + 1) - cry[q];
      float rx = rintf(ccx), ry = rintf(ccy);      // matches jnp.round (half-to-even)
      if (rx >= 0.f && ry >= 0.f && rx < (float)WW && ry < (float)HH)
        tgt[q] = (int)ry * WW + (int)rx;
    }
  }
  // ---- wave-aggregated vote atomics (targets highly redundant within wave) ----
  int lane = threadIdx.x & 63;
  uint32_t* vb = vote + (size_t)b * NPIX;
  #pragma unroll
  for (int q = 0; q < 4; ++q) {
    int tq = tgt[q];
    unsigned long long act = __ballot(tq >= 0);
    while (act) {
      int leader = __ffsll(act) - 1;
      int tl = __shfl(tq, leader);
      unsigned long long mt = __ballot(tq == tl);
      if (lane == leader) atomicAdd(&vb[tl], (uint32_t)__popcll(mt & act));
      act &= ~mt;
    }
  }
}

// ---------------- K2: 7x7 NMS, collect candidates ----------------
__global__ __launch_bounds__(256) void k_nms(const uint32_t* __restrict__ vote,
    uint32_t* __restrict__ cand_cnt, uint32_t* __restrict__ cand_val,
    uint32_t* __restrict__ cand_idx) {
  int i = blockIdx.x * 256 + threadIdx.x;
  int b = i / NPIX, p = i - b * NPIX;
  int h = p / WW, w = p - h * WW;
  uint32_t v = vote[i];
  if (v <= 50u) return;                            // nms > 50.0 <=> count >= 51
  const uint32_t* vb = vote + (size_t)b * NPIX;
  for (int dy = -3; dy <= 3; ++dy) {
    int yy = h + dy; if (yy < 0 || yy >= HH) continue;
    for (int dx = -3; dx <= 3; ++dx) {
      int xx = w + dx; if (xx < 0 || xx >= WW) continue;
      if (vb[yy * WW + xx] > v) return;            // strictly-greater disqualifies (ties kept)
    }
  }
  uint32_t pos = atomicAdd(&cand_cnt[b], 1u);
  if (pos < CAP) {
    cand_val[b * CAP + pos] = v;
    cand_idx[b * CAP + pos] = (uint32_t)((h + PADK) * WPAD + (w + PADK));  // PADDED coords
  }
}

// ---------------- K3: top-200 select with lax.top_k tie order ----------------
__global__ void k_topk(const uint32_t* __restrict__ cand_cnt,
    const uint32_t* __restrict__ cand_val, const uint32_t* __restrict__ cand_idx,
    float* __restrict__ slotx, float* __restrict__ sloty, int* __restrict__ gn0) {
  int b = blockIdx.x;
  int n = (int)cand_cnt[b]; if (n > CAP) n = CAP;
  const uint32_t* cv = cand_val + b * CAP;
  const uint32_t* ci = cand_idx + b * CAP;
  for (int i = threadIdx.x; i < n; i += blockDim.x) {
    unsigned long long ki = ((unsigned long long)cv[i] << 20) | (unsigned long long)(0xFFFFFu - ci[i]);
    int r = 0;
    for (int j = 0; j < n; ++j) {
      unsigned long long kj = ((unsigned long long)cv[j] << 20) | (unsigned long long)(0xFFFFFu - ci[j]);
      r += (kj > ki) ? 1 : 0;                      // value desc, index asc (keys unique)
    }
    if (r < TOPK) {
      uint32_t idx = ci[i];
      slotx[b * TOPK + r] = (float)(idx % WPAD);   // cx = ti % Wp
      sloty[b * TOPK + r] = (float)(idx / WPAD);   // cy = ti // Wp
    }
  }
  if (threadIdx.x == 0) gn0[b] = (n < TOPK) ? n : TOPK;
}

// label of center k (0-based, compacted ascending-slot list) is always k+1.
// 4 px/thread; distance with explicit rn mul/add (no FMA) to bit-match numpy.
__device__ __forceinline__ void assign4(int n, const float* sxs, const float* sys,
    const uchar4 sc4, const float4 r0, const float4 r1, int h, int w, int* l) {
  float ccx[4], ccy[4], bd[4];
  int bi[4];
  float crx[4] = {r0.x, r0.y, r0.z, r0.w};
  float cry[4] = {r1.x, r1.y, r1.z, r1.w};
  #pragma unroll
  for (int q = 0; q < 4; ++q) {
    ccx[q] = (float)(w + q + 1) - crx[q];
    ccy[q] = (float)(h + 1) - cry[q];
    bd[q] = 3.4e38f; bi[q] = 0;
  }
  for (int k = 0; k < n; ++k) {
    float cxk = sxs[k], cyk = sys[k];
    #pragma unroll
    for (int q = 0; q < 4; ++q) {
      float dx = ccx[q] - cxk, dy = ccy[q] - cyk;
      float d = __fadd_rn(__fmul_rn(dx, dx), __fmul_rn(dy, dy));
      if (d < bd[q]) { bd[q] = d; bi[q] = k; }     // strict <: earliest slot wins ties
    }
  }
  unsigned char cls[4] = {sc4.x, sc4.y, sc4.z, sc4.w};
  #pragma unroll
  for (int q = 0; q < 4; ++q) l[q] = (cls[q] >= 24) ? bi[q] + 1 : 0;
}

// ---------------- K4: assign pass0 + count/bbox stats (one row per block) ----------------
__global__ __launch_bounds__(256) void k_assign0(const float* __restrict__ cr,
    const uint8_t* __restrict__ segc, const float* __restrict__ cx,
    const float* __restrict__ cy, const int* __restrict__ ncent,
    int* __restrict__ outlab, uint32_t* __restrict__ gcnt,
    int* __restrict__ gy0, int* __restrict__ gy1,
    int* __restrict__ gx0, int* __restrict__ gx1) {
  int b = blockIdx.y;
  int h = blockIdx.x;                              // block == one row
  __shared__ float sxs[TOPK], sys[TOPK];
  __shared__ uint32_t sc[NSEG];
  __shared__ int sx0[NSEG], sx1[NSEG];
  int n = ncent[b];
  for (int k = threadIdx.x; k < n; k += 256) { sxs[k] = cx[b * TOPK + k]; sys[k] = cy[b * TOPK + k]; }
  for (int j = threadIdx.x; j < NSEG; j += 256) { sc[j] = 0; sx0[j] = INTMAXC; sx1[j] = INTMINC; }
  __syncthreads();
  int w = threadIdx.x * 4;
  size_t i = (size_t)b * NPIX + h * WW + w;
  const float* c0 = cr + (size_t)b * 2 * NPIX + h * WW + w;
  uchar4 sc4 = *reinterpret_cast<const uchar4*>(segc + i);
  float4 r0 = *reinterpret_cast<const float4*>(c0);
  float4 r1 = *reinterpret_cast<const float4*>(c0 + NPIX);
  int l[4];
  if (n == 0) { l[0] = l[1] = l[2] = l[3] = 0; }   // any_c false -> lab0 = 0
  else assign4(n, sxs, sys, sc4, r0, r1, h, w, l);
  *reinterpret_cast<int4*>(outlab + i) = make_int4(l[0], l[1], l[2], l[3]);
  // per-thread run merge -> shared atomics (label-0 stats unused by g1)
  int cur = -1; uint32_t rc = 0; int rx0 = 0, rx1 = 0;
  #pragma unroll
  for (int q = 0; q < 4; ++q) {
    int lq = l[q], x = w + q;
    if (lq == cur) { rc++; rx1 = x; }
    else {
      if (cur > 0) { atomicAdd(&sc[cur], rc); atomicMin(&sx0[cur], rx0); atomicMax(&sx1[cur], rx1); }
      cur = lq; rc = 1; rx0 = rx1 = x;
    }
  }
  if (cur > 0) { atomicAdd(&sc[cur], rc); atomicMin(&sx0[cur], rx0); atomicMax(&sx1[cur], rx1); }
  __syncthreads();
  for (int j = threadIdx.x; j < NSEG; j += 256) {
    if (sc[j]) {
      atomicAdd(&gcnt[b * NSEG + j], sc[j]);
      atomicMin(&gy0[b * NSEG + j], h); atomicMax(&gy1[b * NSEG + j], h);
      atomicMin(&gx0[b * NSEG + j], sx0[j]); atomicMax(&gx1[b * NSEG + j], sx1[j]);
    }
  }
}

// ---------------- K6: bbox-ratio pruning -> compact list 1 ----------------
__global__ void k_build1(const uint32_t* __restrict__ gcnt, const int* __restrict__ gy0,
    const int* __restrict__ gy1, const int* __restrict__ gx0, const int* __restrict__ gx1,
    const float* __restrict__ slotx, const float* __restrict__ sloty,
    float* __restrict__ lx, float* __restrict__ ly, int* __restrict__ gn) {
  int b = blockIdx.x;
  __shared__ int good[TOPK];
  __shared__ int pref[TOPK];
  int k = threadIdx.x;
  if (k < TOPK) {
    uint32_t c = gcnt[b * NSEG + k + 1];
    int g = 0;
    if (c > 0) {
      int j = b * NSEG + k + 1;
      float area = (float)((gy1[j] - gy0[j] + 1) * (gx1[j] - gx0[j] + 1));  // exact (< 2^24)
      float ratio = (float)c / area;               // same IEEE div as reference
      g = (ratio > 0.3f) ? 1 : 0;
    }
    good[k] = g;
  }
  __syncthreads();
  if (threadIdx.x == 0) {
    int s = 0;
    for (int j = 0; j < TOPK; ++j) { pref[j] = s; s += good[j]; }
    gn[b] = s;
  }
  __syncthreads();
  if (k < TOPK && good[k]) {
    int r = pref[k];
    lx[b * TOPK + r] = slotx[b * TOPK + k];
    ly[b * TOPK + r] = sloty[b * TOPK + k];
  }
}

// ---------------- K7: assign pass1 + count/fixed-point cr sums ----------------
__global__ __launch_bounds__(256) void k_assign1(const float* __restrict__ cr,
    const uint8_t* __restrict__ segc, const float* __restrict__ cx,
    const float* __restrict__ cy, const int* __restrict__ ncent,
    const int* __restrict__ fb, int* __restrict__ outlab,
    uint32_t* __restrict__ gcnt, long long* __restrict__ gsx, long long* __restrict__ gsy) {
  int b = blockIdx.y;
  int h = blockIdx.x;
  __shared__ float sxs[TOPK], sys[TOPK];
  __shared__ uint32_t sc[NSEG];
  __shared__ unsigned long long ssx[NSEG], ssy[NSEG];
  int n = ncent[b];
  for (int k = threadIdx.x; k < n; k += 256) { sxs[k] = cx[b * TOPK + k]; sys[k] = cy[b * TOPK + k]; }
  for (int j = threadIdx.x; j < NSEG; j += 256) { sc[j] = 0; ssx[j] = 0; ssy[j] = 0; }
  __syncthreads();
  int w = threadIdx.x * 4;
  size_t i = (size_t)b * NPIX + h * WW + w;
  const float* c0 = cr + (size_t)b * 2 * NPIX + h * WW + w;
  uchar4 sc4 = *reinterpret_cast<const uchar4*>(segc + i);
  float4 r0 = *reinterpret_cast<const float4*>(c0);
  float4 r1 = *reinterpret_cast<const float4*>(c0 + NPIX);
  int l[4];
  if (n == 0) { int4 f = *reinterpret_cast<const int4*>(fb + i); l[0]=f.x; l[1]=f.y; l[2]=f.z; l[3]=f.w; }
  else assign4(n, sxs, sys, sc4, r0, r1, h, w, l);
  *reinterpret_cast<int4*>(outlab + i) = make_int4(l[0], l[1], l[2], l[3]);
  float crx[4] = {r0.x, r0.y, r0.z, r0.w};
  float cry[4] = {r1.x, r1.y, r1.z, r1.w};
  int cur = -1; uint32_t rc = 0; long long ax = 0, ay = 0;
  #pragma unroll
  for (int q = 0; q < 4; ++q) {
    int lq = l[q];
    long long qx = __double2ll_rn((double)crx[q] * 1048576.0);   // 2^20 fixed-point
    long long qy = __double2ll_rn((double)cry[q] * 1048576.0);
    if (lq == cur) { rc++; ax += qx; ay += qy; }
    else {
      if (cur > 0) { atomicAdd(&sc[cur], rc);
                     atomicAdd(&ssx[cur], (unsigned long long)ax);
                     atomicAdd(&ssy[cur], (unsigned long long)ay); }
      cur = lq; rc = 1; ax = qx; ay = qy;
    }
  }
  if (cur > 0) { atomicAdd(&sc[cur], rc);
                 atomicAdd(&ssx[cur], (unsigned long long)ax);
                 atomicAdd(&ssy[cur], (unsigned long long)ay); }
  __syncthreads();
  for (int j = threadIdx.x; j < NSEG; j += 256) {
    if (sc[j]) {
      atomicAdd(&gcnt[b * NSEG + j], sc[j]);
      atomicAdd((unsigned long long*)&gsx[b * NSEG + j], ssx[j]);
      atomicAdd((unsigned long long*)&gsy[b * NSEG + j], ssy[j]);
    }
  }
}

// ---------------- K9: mean pruning -> compact list 2 (ORIGINAL slot coords) ----------------
__global__ void k_build2(const uint32_t* __restrict__ gcnt, const long long* __restrict__ gsx,
    const long long* __restrict__ gsy, const float* __restrict__ slotx,
    const float* __restrict__ sloty, float* __restrict__ lx, float* __restrict__ ly,
    int* __restrict__ gn) {
  int b = blockIdx.x;
  __shared__ int good[TOPK];
  __shared__ int pref[TOPK];
  int k = threadIdx.x;
  if (k < TOPK) {
    uint32_t c = gcnt[b * NSEG + k + 1];           // stats are in COMPACT label space
    int g = 0;
    if (c > 0) {
      double inv = 1.0 / (double)c;
      double mx = ((double)gsx[b * NSEG + k + 1] * (1.0 / 1048576.0)) * inv;
      double my = ((double)gsy[b * NSEG + k + 1] * (1.0 / 1048576.0)) * inv;
      g = (fabs(mx) < 10.0 && fabs(my) < 10.0) ? 1 : 0;
    }
    good[k] = g;
  }
  __syncthreads();
  if (threadIdx.x == 0) {
    int s = 0;
    for (int j = 0; j < TOPK; ++j) { pref[j] = s; s += good[j]; }
    gn[b] = s;
  }
  __syncthreads();
  if (k < TOPK && good[k]) {
    int r = pref[k];
    lx[b * TOPK + r] = slotx[b * TOPK + k];        // reference indexes ORIGINAL sorted coords
    ly[b * TOPK + r] = sloty[b * TOPK + k];
  }
}

// ---------------- K10: assign pass2 + final write + class histogram ----------------
__global__ __launch_bounds__(256) void k_assign2(const float* __restrict__ cr,
    const uint8_t* __restrict__ segc, const float* __restrict__ cx,
    const float* __restrict__ cy, const int* __restrict__ ncent,
    const int* __restrict__ fb, int* __restrict__ outlab,
    float* __restrict__ out_final, uint32_t* __restrict__ hist) {
  int b = blockIdx.y;
  __shared__ float sxs[TOPK], sys[TOPK];
  __shared__ uint32_t sh[NSEG * NCC];
  int n = ncent[b];
  for (int k = threadIdx.x; k < n; k += 256) { sxs[k] = cx[b * TOPK + k]; sys[k] = cy[b * TOPK + k]; }
  for (int j = threadIdx.x; j < NSEG * NCC; j += 256) sh[j] = 0;
  __syncthreads();
  for (int it = 0; it < 4; ++it) {                 // 128 blocks/batch x 4096 px
    int p = blockIdx.x * 4096 + it * 1024 + threadIdx.x * 4;
    int h = p >> 10, w = p & 1023;
    size_t i = (size_t)b * NPIX + p;
    const float* c0 = cr + (size_t)b * 2 * NPIX + p;
    uchar4 sc4 = *reinterpret_cast<const uchar4*>(segc + i);
    float4 r0 = *reinterpret_cast<const float4*>(c0);
    float4 r1 = *reinterpret_cast<const float4*>(c0 + NPIX);
    int l[4];
    if (n == 0) { int4 f = *reinterpret_cast<const int4*>(fb + i); l[0]=f.x; l[1]=f.y; l[2]=f.z; l[3]=f.w; }
    else assign4(n, sxs, sys, sc4, r0, r1, h, w, l);
    *reinterpret_cast<int4*>(outlab + i) = make_int4(l[0], l[1], l[2], l[3]);
    *reinterpret_cast<float4*>(out_final + i) =
        make_float4((float)l[0], (float)l[1], (float)l[2], (float)l[3]);
    unsigned char cls[4] = {sc4.x, sc4.y, sc4.z, sc4.w};
    #pragma unroll
    for (int q = 0; q < 4; ++q) atomicAdd(&sh[l[q] * NCC + cls[q]], 1u);
  }
  __syncthreads();
  for (int j = threadIdx.x; j < NSEG * NCC; j += 256)
    if (sh[j]) atomicAdd(&hist[(size_t)b * NSEG * NCC + j], sh[j]);
}

// ---------------- K12: per-instance mode class + count ----------------
__global__ void k_mode(const uint32_t* __restrict__ hist, int* __restrict__ instc,
    float* __restrict__ out_instc, float* __restrict__ out_cntf) {
  int b = blockIdx.x;
  int j = threadIdx.x;
  if (j >= NSEG) return;
  const uint32_t* hr = hist + ((size_t)b * NSEG + j) * NCC;
  uint32_t bv = hr[0], s = hr[0]; int bc = 0;
  #pragma unroll
  for (int c = 1; c < NCC; ++c) {
    uint32_t v = hr[c]; s += v;
    if (v > bv) { bv = v; bc = c; }                // first-max tie-break
  }
  instc[b * NSEG + j] = bc;
  out_instc[b * NSEG + j] = (float)bc;
  out_cntf[b * NSEG + j] = (float)s;
}

// ---------------- K13: sum softmax prob of instance class per label ----------------
__global__ __launch_bounds__(256) void k_sg(const float* __restrict__ seg,
    const int* __restrict__ lab, const int* __restrict__ instc,
    const float* __restrict__ mbuf, const float* __restrict__ invs,
    long long* __restrict__ Ssel) {
  int b = blockIdx.y;
  __shared__ unsigned long long ss[NSEG];
  __shared__ int icS[NSEG];
  for (int j = threadIdx.x; j < NSEG; j += 256) { ss[j] = 0; icS[j] = instc[b * NSEG + j]; }
  __syncthreads();
  int p = (blockIdx.x * 256 + threadIdx.x) * 4;
  size_t i = (size_t)b * NPIX + p;
  int4 l4 = *reinterpret_cast<const int4*>(lab + i);
  float4 mb = *reinterpret_cast<const float4*>(mbuf + i);
  float4 iv = *reinterpret_cast<const float4*>(invs + i);
  const float* sb = seg + (size_t)b * NCC * NPIX + p;
  int lA[4] = {l4.x, l4.y, l4.z, l4.w};
  float mbA[4] = {mb.x, mb.y, mb.z, mb.w};
  float ivA[4] = {iv.x, iv.y, iv.z, iv.w};
  int cur = -1; long long acc = 0;                 // label 0 IS included here
  #pragma unroll
  for (int q = 0; q < 4; ++q) {
    int lq = lA[q];
    int c = icS[lq];
    float x = sb[(size_t)c * NPIX + q];
    float pr = expf(x - mbA[q]) * ivA[q];
    long long qv = __double2ll_rn((double)pr * 4294967296.0);   // 2^32 fixed-point
    if (lq == cur) acc += qv;
    else { if (cur >= 0) atomicAdd(&ss[cur], (unsigned long long)acc); cur = lq; acc = qv; }
  }
  if (cur >= 0) atomicAdd(&ss[cur], (unsigned long long)acc);
  __syncthreads();
  for (int j = threadIdx.x; j < NSEG; j += 256)
    if (ss[j]) atomicAdd((unsigned long long*)&Ssel[b * NSEG + j], ss[j]);
}

// ---------------- K14: seg_prob = Ssel / max(cntf,1) ----------------
__global__ void k_prob(const long long* __restrict__ Ssel,
    const float* __restrict__ out_cntf, float* __restrict__ out_prob) {
  int i = blockIdx.x * blockDim.x + threadIdx.x;
  if (i >= BB * NSEG) return;
  double s = (double)Ssel[i] * (1.0 / 4294967296.0);
  float c = out_cntf[i];
  out_prob[i] = (float)(s / (double)fmaxf(c, 1.0f));
}

extern "C" void kernel_launch(void* const* d_in, const int* in_sizes, int n_in,
                              void* d_out, int out_size, void* d_ws, size_t ws_size,
                              hipStream_t stream) {
  const float* seg = (const float*)d_in[0];
  const float* cr  = (const float*)d_in[2];
  float* out = (float*)d_out;

  float* out_final  = out;
  float* out_segmap = out + (size_t)BB * NPIX;
  float* out_instc  = out + (size_t)2 * BB * NPIX;
  float* out_prob   = out_instc + BB * NSEG;
  float* out_cntf   = out_prob + BB * NSEG;

  char* ws = (char*)d_ws;
  size_t off = 0;
  auto take = [&](size_t n) { size_t o = off; off += (n + 255) & ~(size_t)255; return o; };

  int32_t*  labA = (int32_t*)(ws + take((size_t)BB * NPIX * 4));  // vote -> lab0 -> final
  int32_t*  labB = (int32_t*)(ws + take((size_t)BB * NPIX * 4));  // lab1
  float*    mbuf = (float*)(ws + take((size_t)BB * NPIX * 4));
  float*    invs = (float*)(ws + take((size_t)BB * NPIX * 4));
  uint8_t*  segc = (uint8_t*)(ws + take((size_t)BB * NPIX));
  // min/max arrays live OUTSIDE the zeroed span (they need INTMAX/INTMIN init;
  // zeroing + re-init from different threads of k_clear would race)
  int* ymin = (int*)(ws + take(BB * NSEG * 4));
  int* ymax = (int*)(ws + take(BB * NSEG * 4));
  int* xmin = (int*)(ws + take(BB * NSEG * 4));
  int* xmax = (int*)(ws + take(BB * NSEG * 4));

  size_t zero_begin = off;
  uint32_t* cand_cnt = (uint32_t*)(ws + take(BB * 4));
  uint32_t* cand_val = (uint32_t*)(ws + take((size_t)BB * CAP * 4));
  uint32_t* cand_idx = (uint32_t*)(ws + take((size_t)BB * CAP * 4));
  float* slotx = (float*)(ws + take(BB * TOPK * 4));
  float* sloty = (float*)(ws + take(BB * TOPK * 4));
  int*   n0 = (int*)(ws + take(BB * 4));
  float* l1x = (float*)(ws + take(BB * TOPK * 4));
  float* l1y = (float*)(ws + take(BB * TOPK * 4));
  int*   n1 = (int*)(ws + take(BB * 4));
  float* l2x = (float*)(ws + take(BB * TOPK * 4));
  float* l2y = (float*)(ws + take(BB * TOPK * 4));
  int*   n2 = (int*)(ws + take(BB * 4));
  uint32_t* cnt0 = (uint32_t*)(ws + take(BB * NSEG * 4));
  uint32_t* cnt2 = (uint32_t*)(ws + take(BB * NSEG * 4));
  long long* sxq = (long long*)(ws + take(BB * NSEG * 8));
  long long* syq = (long long*)(ws + take(BB * NSEG * 8));
  uint32_t* hist = (uint32_t*)(ws + take((size_t)BB * NSEG * NCC * 4));
  int* instc = (int*)(ws + take(BB * NSEG * 4));
  long long* Ssel = (long long*)(ws + take(BB * NSEG * 8));
  size_t zero_end = off;

  if (ws_size < off) return;  // workspace too small -> fail visibly

  int nsm = (int)((zero_end - zero_begin) / 16);   // 256-aligned span -> uint4 count
  k_clear<<<BB * NPIX / 4 / 256, 256, 0, stream>>>((uint4*)labA,
      (uint4*)(ws + zero_begin), nsm, ymin, ymax, xmin, xmax);

  k_pixel<<<BB * NPIX / 4 / 256, 256, 0, stream>>>(seg, cr, out_segmap,
      (uint32_t*)labA, mbuf, invs, segc);
  k_nms<<<BB * NPIX / 256, 256, 0, stream>>>((const uint32_t*)labA,
      cand_cnt, cand_val, cand_idx);
  k_topk<<<BB, 256, 0, stream>>>(cand_cnt, cand_val, cand_idx, slotx, sloty, n0);

  dim3 rgrid(HH, BB);                              // one row per block

  // pass 0: all top-k candidates (fallback 0) + cnt/bbox stats
  k_assign0<<<rgrid, 256, 0, stream>>>(cr, segc, slotx, sloty, n0, labA,
      cnt0, ymin, ymax, xmin, xmax);
  k_build1<<<BB, 256, 0, stream>>>(cnt0, ymin, ymax, xmin, xmax, slotx, sloty, l1x, l1y, n1);
  // pass 1: ratio-pruned compact list (fallback lab0) + cnt/cr-sum stats
  k_assign1<<<rgrid, 256, 0, stream>>>(cr, segc, l1x, l1y, n1, labA, labB, cnt2, sxq, syq);
  k_build2<<<BB, 256, 0, stream>>>(cnt2, sxq, syq, slotx, sloty, l2x, l2y, n2);
  // pass 2: mean-pruned compact list (fallback lab1) + final write + histogram
  k_assign2<<<dim3(128, BB), 256, 0, stream>>>(cr, segc, l2x, l2y, n2, labB, labA,
      out_final, hist);

  k_mode<<<BB, 256, 0, stream>>>(hist, instc, out_instc, out_cntf);
  k_sg<<<dim3(NPIX / 1024, BB), 256, 0, stream>>>(seg, labA, instc, mbuf, invs, Ssel);
  k_prob<<<(BB * NSEG + 255) / 256, 256, 0, stream>>>(Ssel, out_cntf, out_prob);
}

// Round 4
// 146.552 us; speedup vs baseline: 2.1693x; 1.1535x over previous
//
#include <hip/hip_runtime.h>
#include <stdint.h>

#define HH   512
#define WW   1024
#define BB   2
#define NCC  34
#define PADK 7
#define TOPK 200
#define NSEG (TOPK + 1)
#define WPAD (WW + 2 * PADK)   // 1038
#define NPIX (HH * WW)         // 524288
#define CAP  12288
#define INTMAXC  0x7FFFFFFF
#define INTMINC  (-0x7FFFFFFF - 1)

// ---------------- K0: clear votes + accumulators, init min/max ----------------
__global__ __launch_bounds__(256) void k_clear(uint4* __restrict__ votes,
    uint4* __restrict__ small, int nsm, int* __restrict__ y0, int* __restrict__ y1,
    int* __restrict__ x0, int* __restrict__ x1) {
  int t = blockIdx.x * 256 + threadIdx.x;
  if (t < BB * NPIX / 4) votes[t] = make_uint4(0u, 0u, 0u, 0u);
  if (t < nsm) small[t] = make_uint4(0u, 0u, 0u, 0u);
  if (t < BB * NSEG) { y0[t] = INTMAXC; y1[t] = INTMINC; x0[t] = INTMAXC; x1[t] = INTMINC; }
}

// ---------------- K1: per-pixel fused pass (4 px/thread, online softmax) ----------------
__global__ __launch_bounds__(256) void k_pixel(const float* __restrict__ seg,
    const float* __restrict__ cr, float* __restrict__ out_segmap,
    uint32_t* __restrict__ vote, float* __restrict__ mbuf,
    float* __restrict__ invs, uint8_t* __restrict__ segc) {
  int t = blockIdx.x * 256 + threadIdx.x;          // [0, BB*NPIX/4)
  int b = t >> 17;                                 // NPIX/4 = 131072 = 2^17
  int p = (t & 131071) << 2;
  int h = p >> 10, w = p & 1023;
  size_t i = (size_t)b * NPIX + p;
  const float* base = seg + (size_t)b * NCC * NPIX + p;

  float4 m = *reinterpret_cast<const float4*>(base);
  float4 s = make_float4(1.f, 1.f, 1.f, 1.f);
  int4 am = make_int4(0, 0, 0, 0);
  for (int c = 1; c < NCC; ++c) {
    float4 x = *reinterpret_cast<const float4*>(base + (size_t)c * NPIX);
    // branchless online softmax: exp(0)==1 exactly, so result == two-pass sum
    { float mn = fmaxf(m.x, x.x); s.x = s.x * expf(m.x - mn) + expf(x.x - mn); if (x.x > m.x) am.x = c; m.x = mn; }
    { float mn = fmaxf(m.y, x.y); s.y = s.y * expf(m.y - mn) + expf(x.y - mn); if (x.y > m.y) am.y = c; m.y = mn; }
    { float mn = fmaxf(m.z, x.z); s.z = s.z * expf(m.z - mn) + expf(x.z - mn); if (x.z > m.z) am.z = c; m.z = mn; }
    { float mn = fmaxf(m.w, x.w); s.w = s.w * expf(m.w - mn) + expf(x.w - mn); if (x.w > m.w) am.w = c; m.w = mn; }
  }
  *reinterpret_cast<float4*>(out_segmap + i) =
      make_float4((float)am.x, (float)am.y, (float)am.z, (float)am.w);
  *reinterpret_cast<uchar4*>(segc + i) =
      make_uchar4((unsigned char)am.x, (unsigned char)am.y, (unsigned char)am.z, (unsigned char)am.w);
  *reinterpret_cast<float4*>(mbuf + i) = m;
  *reinterpret_cast<float4*>(invs + i) = make_float4(1.f / s.x, 1.f / s.y, 1.f / s.z, 1.f / s.w);

  // ---- vote targets ----
  const float* c0 = cr + (size_t)b * 2 * NPIX + p;
  float4 r0 = *reinterpret_cast<const float4*>(c0);
  float4 r1 = *reinterpret_cast<const float4*>(c0 + NPIX);
  float crx[4] = {r0.x, r0.y, r0.z, r0.w};
  float cry[4] = {r1.x, r1.y, r1.z, r1.w};
  int amA[4] = {am.x, am.y, am.z, am.w};
  int tgt[4];
  #pragma unroll
  for (int q = 0; q < 4; ++q) {
    tgt[q] = -1;
    if (amA[q] >= 24) {                            // "things": class in (23.99, 33]
      float ccx = (float)(w + q + 1) - crx[q];
      float ccy = (float)(h + 1) - cry[q];
      float rx = rintf(ccx), ry = rintf(ccy);      // matches jnp.round (half-to-even)
      if (rx >= 0.f && ry >= 0.f && rx < (float)WW && ry < (float)HH)
        tgt[q] = (int)ry * WW + (int)rx;
    }
  }
  // ---- wave-aggregated vote atomics (targets highly redundant within wave) ----
  int lane = threadIdx.x & 63;
  uint32_t* vb = vote + (size_t)b * NPIX;
  #pragma unroll
  for (int q = 0; q < 4; ++q) {
    int tq = tgt[q];
    unsigned long long act = __ballot(tq >= 0);
    while (act) {
      int leader = __ffsll(act) - 1;
      int tl = __shfl(tq, leader);
      unsigned long long mt = __ballot(tq == tl);
      if (lane == leader) atomicAdd(&vb[tl], (uint32_t)__popcll(mt & act));
      act &= ~mt;
    }
  }
}

// ---------------- K2: 7x7 NMS (4 px/thread), collect candidates ----------------
__global__ __launch_bounds__(256) void k_nms(const uint32_t* __restrict__ vote,
    uint32_t* __restrict__ cand_cnt, uint32_t* __restrict__ cand_val,
    uint32_t* __restrict__ cand_idx) {
  int t = blockIdx.x * 256 + threadIdx.x;
  int b = t >> 17;
  int p = (t & 131071) << 2;
  int h = p >> 10, w0 = p & 1023;
  const uint32_t* vb = vote + (size_t)b * NPIX;
  uint4 v4 = *reinterpret_cast<const uint4*>(vb + p);
  uint32_t vv[4] = {v4.x, v4.y, v4.z, v4.w};
  #pragma unroll
  for (int q = 0; q < 4; ++q) {
    uint32_t v = vv[q];
    if (v <= 50u) continue;                        // nms > 50.0 <=> count >= 51
    int w = w0 + q;
    bool peak = true;
    for (int dy = -3; dy <= 3 && peak; ++dy) {
      int yy = h + dy; if (yy < 0 || yy >= HH) continue;
      for (int dx = -3; dx <= 3; ++dx) {
        int xx = w + dx; if (xx < 0 || xx >= WW) continue;
        if (vb[yy * WW + xx] > v) { peak = false; break; }   // strict > disqualifies
      }
    }
    if (!peak) continue;
    uint32_t pos = atomicAdd(&cand_cnt[b], 1u);
    if (pos < CAP) {
      cand_val[b * CAP + pos] = v;
      cand_idx[b * CAP + pos] = (uint32_t)((h + PADK) * WPAD + (w + PADK));  // PADDED coords
    }
  }
}

// ---------------- K3: top-200 select with lax.top_k tie order ----------------
__global__ void k_topk(const uint32_t* __restrict__ cand_cnt,
    const uint32_t* __restrict__ cand_val, const uint32_t* __restrict__ cand_idx,
    float* __restrict__ slotx, float* __restrict__ sloty, int* __restrict__ gn0) {
  int b = blockIdx.x;
  int n = (int)cand_cnt[b]; if (n > CAP) n = CAP;
  const uint32_t* cv = cand_val + b * CAP;
  const uint32_t* ci = cand_idx + b * CAP;
  for (int i = threadIdx.x; i < n; i += blockDim.x) {
    unsigned long long ki = ((unsigned long long)cv[i] << 20) | (unsigned long long)(0xFFFFFu - ci[i]);
    int r = 0;
    for (int j = 0; j < n; ++j) {
      unsigned long long kj = ((unsigned long long)cv[j] << 20) | (unsigned long long)(0xFFFFFu - ci[j]);
      r += (kj > ki) ? 1 : 0;                      // value desc, index asc (keys unique)
    }
    if (r < TOPK) {
      uint32_t idx = ci[i];
      slotx[b * TOPK + r] = (float)(idx % WPAD);   // cx = ti % Wp
      sloty[b * TOPK + r] = (float)(idx / WPAD);   // cy = ti // Wp
    }
  }
  if (threadIdx.x == 0) gn0[b] = (n < TOPK) ? n : TOPK;
}

// ---------------- per-wave conservative center prune ----------------
// Keeps (ascending k) every center that could be the argmin for ANY point in
// the wave's pixel bbox. Conservative slack 0.5px on radii + 1.0 on UB, vastly
// exceeding float rounding (values <= ~2e6, ulp <= 0.25). Exact distances are
// re-evaluated later, so prune only needs to be conservative, not exact.
__device__ __forceinline__ int prune_centers(int n, const float* __restrict__ sxs,
    const float* __restrict__ sys, float minx, float maxx, float miny, float maxy,
    short* __restrict__ clist, int lane) {
  #pragma unroll
  for (int o = 32; o; o >>= 1) {
    minx = fminf(minx, __shfl_xor(minx, o));
    maxx = fmaxf(maxx, __shfl_xor(maxx, o));
    miny = fminf(miny, __shfl_xor(miny, o));
    maxy = fmaxf(maxy, __shfl_xor(maxy, o));
  }
  float cx0 = 0.5f * (minx + maxx), rx = 0.5f * (maxx - minx) + 0.5f;
  float cy0 = 0.5f * (miny + maxy), ry = 0.5f * (maxy - miny) + 0.5f;
  float lo[4];
  float ub = 3.4e38f;
  #pragma unroll
  for (int c = 0; c < 4; ++c) {
    int k = c * 64 + lane;
    float l = 3.4e38f;
    if (k < n) {
      float dx = fabsf(sxs[k] - cx0), dy = fabsf(sys[k] - cy0);
      float hx = dx + rx, hy = dy + ry;
      ub = fminf(ub, hx * hx + hy * hy);
      float lx = fmaxf(dx - rx, 0.f), ly = fmaxf(dy - ry, 0.f);
      l = lx * lx + ly * ly;
    }
    lo[c] = l;
  }
  #pragma unroll
  for (int o = 32; o; o >>= 1) ub = fminf(ub, __shfl_xor(ub, o));
  ub += 1.0f;
  int m = 0;
  unsigned long long lmlt = (1ull << lane) - 1ull;
  #pragma unroll
  for (int c = 0; c < 4; ++c) {                    // chunk-major => ascending k
    int k = c * 64 + lane;
    bool keep = (k < n) && (lo[c] <= ub);
    unsigned long long msk = __ballot(keep);
    if (keep) clist[m + (int)__popcll(msk & lmlt)] = (short)k;
    m += (int)__popcll(msk);
  }
  return m;
}

// exact argmin over pruned candidate list (ascending original k, strict <)
__device__ __forceinline__ void assign4_exact(int m, const short* __restrict__ clist,
    const float* __restrict__ sxs, const float* __restrict__ sys,
    const float* ccx, const float* ccy, const unsigned char* cls, int* l) {
  float bd[4] = {3.4e38f, 3.4e38f, 3.4e38f, 3.4e38f};
  int bk[4] = {0, 0, 0, 0};
  for (int j = 0; j < m; ++j) {
    int k = (int)clist[j];
    float cxk = sxs[k], cyk = sys[k];
    #pragma unroll
    for (int q = 0; q < 4; ++q) {
      float dx = ccx[q] - cxk, dy = ccy[q] - cyk;
      float d = __fadd_rn(__fmul_rn(dx, dx), __fmul_rn(dy, dy));  // no FMA: bit-match numpy
      if (d < bd[q]) { bd[q] = d; bk[q] = k; }
    }
  }
  #pragma unroll
  for (int q = 0; q < 4; ++q) l[q] = (cls[q] >= 24) ? bk[q] + 1 : 0;
}

// ---------------- K4: assign pass0 + count/bbox stats (one row per block) ----------------
__global__ __launch_bounds__(256) void k_assign0(const float* __restrict__ cr,
    const uint8_t* __restrict__ segc, const float* __restrict__ cx,
    const float* __restrict__ cy, const int* __restrict__ ncent,
    int* __restrict__ outlab, uint32_t* __restrict__ gcnt,
    int* __restrict__ gy0, int* __restrict__ gy1,
    int* __restrict__ gx0, int* __restrict__ gx1) {
  int b = blockIdx.y;
  int h = blockIdx.x;                              // block == one row
  __shared__ float sxs[TOPK], sys[TOPK];
  __shared__ uint32_t sc[NSEG];
  __shared__ int sx0[NSEG], sx1[NSEG];
  __shared__ short clists[4][TOPK];
  int n = ncent[b];
  for (int k = threadIdx.x; k < n; k += 256) { sxs[k] = cx[b * TOPK + k]; sys[k] = cy[b * TOPK + k]; }
  for (int j = threadIdx.x; j < NSEG; j += 256) { sc[j] = 0; sx0[j] = INTMAXC; sx1[j] = INTMINC; }
  __syncthreads();
  int w = threadIdx.x * 4;
  size_t i = (size_t)b * NPIX + h * WW + w;
  const float* c0 = cr + (size_t)b * 2 * NPIX + h * WW + w;
  uchar4 sc4 = *reinterpret_cast<const uchar4*>(segc + i);
  float4 r0 = *reinterpret_cast<const float4*>(c0);
  float4 r1 = *reinterpret_cast<const float4*>(c0 + NPIX);
  int l[4];
  if (n == 0) { l[0] = l[1] = l[2] = l[3] = 0; }   // any_c false -> lab0 = 0
  else {
    float ccx[4], ccy[4];
    #pragma unroll
    for (int q = 0; q < 4; ++q) {
      ccx[q] = (float)(w + q + 1) - ((const float*)&r0)[q];
      ccy[q] = (float)(h + 1) - ((const float*)&r1)[q];
    }
    float mnx = fminf(fminf(ccx[0], ccx[1]), fminf(ccx[2], ccx[3]));
    float mxx = fmaxf(fmaxf(ccx[0], ccx[1]), fmaxf(ccx[2], ccx[3]));
    float mny = fminf(fminf(ccy[0], ccy[1]), fminf(ccy[2], ccy[3]));
    float mxy = fmaxf(fmaxf(ccy[0], ccy[1]), fmaxf(ccy[2], ccy[3]));
    int lane = threadIdx.x & 63, wv = threadIdx.x >> 6;
    int m = prune_centers(n, sxs, sys, mnx, mxx, mny, mxy, clists[wv], lane);
    unsigned char cls[4] = {sc4.x, sc4.y, sc4.z, sc4.w};
    assign4_exact(m, clists[wv], sxs, sys, ccx, ccy, cls, l);
  }
  *reinterpret_cast<int4*>(outlab + i) = make_int4(l[0], l[1], l[2], l[3]);
  // per-thread run merge -> shared atomics (label-0 stats unused by g1)
  int cur = -1; uint32_t rc = 0; int rx0 = 0, rx1 = 0;
  #pragma unroll
  for (int q = 0; q < 4; ++q) {
    int lq = l[q], x = w + q;
    if (lq == cur) { rc++; rx1 = x; }
    else {
      if (cur > 0) { atomicAdd(&sc[cur], rc); atomicMin(&sx0[cur], rx0); atomicMax(&sx1[cur], rx1); }
      cur = lq; rc = 1; rx0 = rx1 = x;
    }
  }
  if (cur > 0) { atomicAdd(&sc[cur], rc); atomicMin(&sx0[cur], rx0); atomicMax(&sx1[cur], rx1); }
  __syncthreads();
  for (int j = threadIdx.x; j < NSEG; j += 256) {
    if (sc[j]) {
      atomicAdd(&gcnt[b * NSEG + j], sc[j]);
      atomicMin(&gy0[b * NSEG + j], h); atomicMax(&gy1[b * NSEG + j], h);
      atomicMin(&gx0[b * NSEG + j], sx0[j]); atomicMax(&gx1[b * NSEG + j], sx1[j]);
    }
  }
}

// ---------------- K6: bbox-ratio pruning -> compact list 1 ----------------
__global__ void k_build1(const uint32_t* __restrict__ gcnt, const int* __restrict__ gy0,
    const int* __restrict__ gy1, const int* __restrict__ gx0, const int* __restrict__ gx1,
    const float* __restrict__ slotx, const float* __restrict__ sloty,
    float* __restrict__ lx, float* __restrict__ ly, int* __restrict__ gn) {
  int b = blockIdx.x;
  __shared__ int good[TOPK];
  __shared__ int pref[TOPK];
  int k = threadIdx.x;
  if (k < TOPK) {
    uint32_t c = gcnt[b * NSEG + k + 1];
    int g = 0;
    if (c > 0) {
      int j = b * NSEG + k + 1;
      float area = (float)((gy1[j] - gy0[j] + 1) * (gx1[j] - gx0[j] + 1));  // exact (< 2^24)
      float ratio = (float)c / area;               // same IEEE div as reference
      g = (ratio > 0.3f) ? 1 : 0;
    }
    good[k] = g;
  }
  __syncthreads();
  if (threadIdx.x == 0) {
    int s = 0;
    for (int j = 0; j < TOPK; ++j) { pref[j] = s; s += good[j]; }
    gn[b] = s;
  }
  __syncthreads();
  if (k < TOPK && good[k]) {
    int r = pref[k];
    lx[b * TOPK + r] = slotx[b * TOPK + k];
    ly[b * TOPK + r] = sloty[b * TOPK + k];
  }
}

// ---------------- K7: assign pass1 + count/fixed-point cr sums ----------------
__global__ __launch_bounds__(256) void k_assign1(const float* __restrict__ cr,
    const uint8_t* __restrict__ segc, const float* __restrict__ cx,
    const float* __restrict__ cy, const int* __restrict__ ncent,
    const int* __restrict__ fb, int* __restrict__ outlab,
    uint32_t* __restrict__ gcnt, long long* __restrict__ gsx, long long* __restrict__ gsy) {
  int b = blockIdx.y;
  int h = blockIdx.x;
  __shared__ float sxs[TOPK], sys[TOPK];
  __shared__ uint32_t sc[NSEG];
  __shared__ unsigned long long ssx[NSEG], ssy[NSEG];
  __shared__ short clists[4][TOPK];
  int n = ncent[b];
  for (int k = threadIdx.x; k < n; k += 256) { sxs[k] = cx[b * TOPK + k]; sys[k] = cy[b * TOPK + k]; }
  for (int j = threadIdx.x; j < NSEG; j += 256) { sc[j] = 0; ssx[j] = 0; ssy[j] = 0; }
  __syncthreads();
  int w = threadIdx.x * 4;
  size_t i = (size_t)b * NPIX + h * WW + w;
  const float* c0 = cr + (size_t)b * 2 * NPIX + h * WW + w;
  uchar4 sc4 = *reinterpret_cast<const uchar4*>(segc + i);
  float4 r0 = *reinterpret_cast<const float4*>(c0);
  float4 r1 = *reinterpret_cast<const float4*>(c0 + NPIX);
  int l[4];
  if (n == 0) { int4 f = *reinterpret_cast<const int4*>(fb + i); l[0]=f.x; l[1]=f.y; l[2]=f.z; l[3]=f.w; }
  else {
    float ccx[4], ccy[4];
    #pragma unroll
    for (int q = 0; q < 4; ++q) {
      ccx[q] = (float)(w + q + 1) - ((const float*)&r0)[q];
      ccy[q] = (float)(h + 1) - ((const float*)&r1)[q];
    }
    float mnx = fminf(fminf(ccx[0], ccx[1]), fminf(ccx[2], ccx[3]));
    float mxx = fmaxf(fmaxf(ccx[0], ccx[1]), fmaxf(ccx[2], ccx[3]));
    float mny = fminf(fminf(ccy[0], ccy[1]), fminf(ccy[2], ccy[3]));
    float mxy = fmaxf(fmaxf(ccy[0], ccy[1]), fmaxf(ccy[2], ccy[3]));
    int lane = threadIdx.x & 63, wv = threadIdx.x >> 6;
    int m = prune_centers(n, sxs, sys, mnx, mxx, mny, mxy, clists[wv], lane);
    unsigned char cls[4] = {sc4.x, sc4.y, sc4.z, sc4.w};
    assign4_exact(m, clists[wv], sxs, sys, ccx, ccy, cls, l);
  }
  *reinterpret_cast<int4*>(outlab + i) = make_int4(l[0], l[1], l[2], l[3]);
  float crx[4] = {r0.x, r0.y, r0.z, r0.w};
  float cry[4] = {r1.x, r1.y, r1.z, r1.w};
  int cur = -1; uint32_t rc = 0; long long ax = 0, ay = 0;
  #pragma unroll
  for (int q = 0; q < 4; ++q) {
    int lq = l[q];
    long long qx = __double2ll_rn((double)crx[q] * 1048576.0);   // 2^20 fixed-point
    long long qy = __double2ll_rn((double)cry[q] * 1048576.0);
    if (lq == cur) { rc++; ax += qx; ay += qy; }
    else {
      if (cur > 0) { atomicAdd(&sc[cur], rc);
                     atomicAdd(&ssx[cur], (unsigned long long)ax);
                     atomicAdd(&ssy[cur], (unsigned long long)ay); }
      cur = lq; rc = 1; ax = qx; ay = qy;
    }
  }
  if (cur > 0) { atomicAdd(&sc[cur], rc);
                 atomicAdd(&ssx[cur], (unsigned long long)ax);
                 atomicAdd(&ssy[cur], (unsigned long long)ay); }
  __syncthreads();
  for (int j = threadIdx.x; j < NSEG; j += 256) {
    if (sc[j]) {
      atomicAdd(&gcnt[b * NSEG + j], sc[j]);
      atomicAdd((unsigned long long*)&gsx[b * NSEG + j], ssx[j]);
      atomicAdd((unsigned long long*)&gsy[b * NSEG + j], ssy[j]);
    }
  }
}

// ---------------- K9: mean pruning -> compact list 2 (ORIGINAL slot coords) ----------------
__global__ void k_build2(const uint32_t* __restrict__ gcnt, const long long* __restrict__ gsx,
    const long long* __restrict__ gsy, const float* __restrict__ slotx,
    const float* __restrict__ sloty, float* __restrict__ lx, float* __restrict__ ly,
    int* __restrict__ gn) {
  int b = blockIdx.x;
  __shared__ int good[TOPK];
  __shared__ int pref[TOPK];
  int k = threadIdx.x;
  if (k < TOPK) {
    uint32_t c = gcnt[b * NSEG + k + 1];           // stats are in COMPACT label space
    int g = 0;
    if (c > 0) {
      double inv = 1.0 / (double)c;
      double mx = ((double)gsx[b * NSEG + k + 1] * (1.0 / 1048576.0)) * inv;
      double my = ((double)gsy[b * NSEG + k + 1] * (1.0 / 1048576.0)) * inv;
      g = (fabs(mx) < 10.0 && fabs(my) < 10.0) ? 1 : 0;
    }
    good[k] = g;
  }
  __syncthreads();
  if (threadIdx.x == 0) {
    int s = 0;
    for (int j = 0; j < TOPK; ++j) { pref[j] = s; s += good[j]; }
    gn[b] = s;
  }
  __syncthreads();
  if (k < TOPK && good[k]) {
    int r = pref[k];
    lx[b * TOPK + r] = slotx[b * TOPK + k];        // reference indexes ORIGINAL sorted coords
    ly[b * TOPK + r] = sloty[b * TOPK + k];
  }
}

// ---------------- K10: assign pass2 + final write + class histogram ----------------
__global__ __launch_bounds__(256) void k_assign2(const float* __restrict__ cr,
    const uint8_t* __restrict__ segc, const float* __restrict__ cx,
    const float* __restrict__ cy, const int* __restrict__ ncent,
    const int* __restrict__ fb, int* __restrict__ outlab,
    float* __restrict__ out_final, uint32_t* __restrict__ hist) {
  int b = blockIdx.y;
  __shared__ float sxs[TOPK], sys[TOPK];
  __shared__ uint32_t sh[NSEG * NCC];
  __shared__ short clists[4][TOPK];
  int n = ncent[b];
  for (int k = threadIdx.x; k < n; k += 256) { sxs[k] = cx[b * TOPK + k]; sys[k] = cy[b * TOPK + k]; }
  for (int j = threadIdx.x; j < NSEG * NCC; j += 256) sh[j] = 0;
  __syncthreads();
  // 128 blocks/batch x 4096 px; per thread: same x, 4 consecutive rows
  float ccxA[4][4], ccyA[4][4];
  uchar4 sc4A[4];
  int4 fbA[4];
  float mnx = 3.4e38f, mxx = -3.4e38f, mny = 3.4e38f, mxy = -3.4e38f;
  #pragma unroll
  for (int it = 0; it < 4; ++it) {
    int p = blockIdx.x * 4096 + it * 1024 + threadIdx.x * 4;
    int h = p >> 10, w = p & 1023;
    size_t i = (size_t)b * NPIX + p;
    const float* c0 = cr + (size_t)b * 2 * NPIX + p;
    sc4A[it] = *reinterpret_cast<const uchar4*>(segc + i);
    float4 r0 = *reinterpret_cast<const float4*>(c0);
    float4 r1 = *reinterpret_cast<const float4*>(c0 + NPIX);
    if (n == 0) fbA[it] = *reinterpret_cast<const int4*>(fb + i);
    #pragma unroll
    for (int q = 0; q < 4; ++q) {
      float cxv = (float)(w + q + 1) - ((const float*)&r0)[q];
      float cyv = (float)(h + 1) - ((const float*)&r1)[q];
      ccxA[it][q] = cxv; ccyA[it][q] = cyv;
      mnx = fminf(mnx, cxv); mxx = fmaxf(mxx, cxv);
      mny = fminf(mny, cyv); mxy = fmaxf(mxy, cyv);
    }
  }
  int m = 0;
  int lane = threadIdx.x & 63, wv = threadIdx.x >> 6;
  if (n > 0) m = prune_centers(n, sxs, sys, mnx, mxx, mny, mxy, clists[wv], lane);
  int curk = -1; uint32_t rc = 0;
  #pragma unroll
  for (int it = 0; it < 4; ++it) {
    int p = blockIdx.x * 4096 + it * 1024 + threadIdx.x * 4;
    size_t i = (size_t)b * NPIX + p;
    int l[4];
    if (n == 0) { l[0] = fbA[it].x; l[1] = fbA[it].y; l[2] = fbA[it].z; l[3] = fbA[it].w; }
    else {
      unsigned char cls[4] = {sc4A[it].x, sc4A[it].y, sc4A[it].z, sc4A[it].w};
      assign4_exact(m, clists[wv], sxs, sys, ccxA[it], ccyA[it], cls, l);
    }
    *reinterpret_cast<int4*>(outlab + i) = make_int4(l[0], l[1], l[2], l[3]);
    *reinterpret_cast<float4*>(out_final + i) =
        make_float4((float)l[0], (float)l[1], (float)l[2], (float)l[3]);
    unsigned char cls[4] = {sc4A[it].x, sc4A[it].y, sc4A[it].z, sc4A[it].w};
    #pragma unroll
    for (int q = 0; q < 4; ++q) {                  // run-merge hist atomics
      int key = l[q] * NCC + (int)cls[q];
      if (key == curk) { rc++; }
      else { if (curk >= 0) atomicAdd(&sh[curk], rc); curk = key; rc = 1; }
    }
  }
  if (curk >= 0) atomicAdd(&sh[curk], rc);
  __syncthreads();
  for (int j = threadIdx.x; j < NSEG * NCC; j += 256)
    if (sh[j]) atomicAdd(&hist[(size_t)b * NSEG * NCC + j], sh[j]);
}

// ---------------- K12: per-instance mode class + count ----------------
__global__ void k_mode(const uint32_t* __restrict__ hist, int* __restrict__ instc,
    float* __restrict__ out_instc, float* __restrict__ out_cntf) {
  int b = blockIdx.x;
  int j = threadIdx.x;
  if (j >= NSEG) return;
  const uint32_t* hr = hist + ((size_t)b * NSEG + j) * NCC;
  uint32_t bv = hr[0], s = hr[0]; int bc = 0;
  #pragma unroll
  for (int c = 1; c < NCC; ++c) {
    uint32_t v = hr[c]; s += v;
    if (v > bv) { bv = v; bc = c; }                // first-max tie-break
  }
  instc[b * NSEG + j] = bc;
  out_instc[b * NSEG + j] = (float)bc;
  out_cntf[b * NSEG + j] = (float)s;
}

// ---------------- K13: sum softmax prob of instance class per label ----------------
__global__ __launch_bounds__(256) void k_sg(const float* __restrict__ seg,
    const int* __restrict__ lab, const int* __restrict__ instc,
    const float* __restrict__ mbuf, const float* __restrict__ invs,
    long long* __restrict__ Ssel) {
  int b = blockIdx.y;
  __shared__ unsigned long long ss[NSEG];
  __shared__ int icS[NSEG];
  for (int j = threadIdx.x; j < NSEG; j += 256) { ss[j] = 0; icS[j] = instc[b * NSEG + j]; }
  __syncthreads();
  int p = (blockIdx.x * 256 + threadIdx.x) * 4;
  size_t i = (size_t)b * NPIX + p;
  int4 l4 = *reinterpret_cast<const int4*>(lab + i);
  float4 mb = *reinterpret_cast<const float4*>(mbuf + i);
  float4 iv = *reinterpret_cast<const float4*>(invs + i);
  const float* sb = seg + (size_t)b * NCC * NPIX + p;
  int lA[4] = {l4.x, l4.y, l4.z, l4.w};
  float mbA[4] = {mb.x, mb.y, mb.z, mb.w};
  float ivA[4] = {iv.x, iv.y, iv.z, iv.w};
  int cur = -1; long long acc = 0;                 // label 0 IS included here
  #pragma unroll
  for (int q = 0; q < 4; ++q) {
    int lq = lA[q];
    int c = icS[lq];
    float x = sb[(size_t)c * NPIX + q];
    float pr = expf(x - mbA[q]) * ivA[q];
    long long qv = __double2ll_rn((double)pr * 4294967296.0);   // 2^32 fixed-point
    if (lq == cur) acc += qv;
    else { if (cur >= 0) atomicAdd(&ss[cur], (unsigned long long)acc); cur = lq; acc = qv; }
  }
  if (cur >= 0) atomicAdd(&ss[cur], (unsigned long long)acc);
  __syncthreads();
  for (int j = threadIdx.x; j < NSEG; j += 256)
    if (ss[j]) atomicAdd((unsigned long long*)&Ssel[b * NSEG + j], ss[j]);
}

// ---------------- K14: seg_prob = Ssel / max(cntf,1) ----------------
__global__ void k_prob(const long long* __restrict__ Ssel,
    const float* __restrict__ out_cntf, float* __restrict__ out_prob) {
  int i = blockIdx.x * blockDim.x + threadIdx.x;
  if (i >= BB * NSEG) return;
  double s = (double)Ssel[i] * (1.0 / 4294967296.0);
  float c = out_cntf[i];
  out_prob[i] = (float)(s / (double)fmaxf(c, 1.0f));
}

extern "C" void kernel_launch(void* const* d_in, const int* in_sizes, int n_in,
                              void* d_out, int out_size, void* d_ws, size_t ws_size,
                              hipStream_t stream) {
  const float* seg = (const float*)d_in[0];
  const float* cr  = (const float*)d_in[2];
  float* out = (float*)d_out;

  float* out_final  = out;
  float* out_segmap = out + (size_t)BB * NPIX;
  float* out_instc  = out + (size_t)2 * BB * NPIX;
  float* out_prob   = out_instc + BB * NSEG;
  float* out_cntf   = out_prob + BB * NSEG;

  char* ws = (char*)d_ws;
  size_t off = 0;
  auto take = [&](size_t n) { size_t o = off; off += (n + 255) & ~(size_t)255; return o; };

  int32_t*  labA = (int32_t*)(ws + take((size_t)BB * NPIX * 4));  // vote -> lab0 -> final
  int32_t*  labB = (int32_t*)(ws + take((size_t)BB * NPIX * 4));  // lab1
  float*    mbuf = (float*)(ws + take((size_t)BB * NPIX * 4));
  float*    invs = (float*)(ws + take((size_t)BB * NPIX * 4));
  uint8_t*  segc = (uint8_t*)(ws + take((size_t)BB * NPIX));
  // min/max arrays OUTSIDE the zeroed span (need INTMAX/INTMIN init)
  int* ymin = (int*)(ws + take(BB * NSEG * 4));
  int* ymax = (int*)(ws + take(BB * NSEG * 4));
  int* xmin = (int*)(ws + take(BB * NSEG * 4));
  int* xmax = (int*)(ws + take(BB * NSEG * 4));

  size_t zero_begin = off;
  uint32_t* cand_cnt = (uint32_t*)(ws + take(BB * 4));
  uint32_t* cand_val = (uint32_t*)(ws + take((size_t)BB * CAP * 4));
  uint32_t* cand_idx = (uint32_t*)(ws + take((size_t)BB * CAP * 4));
  float* slotx = (float*)(ws + take(BB * TOPK * 4));
  float* sloty = (float*)(ws + take(BB * TOPK * 4));
  int*   n0 = (int*)(ws + take(BB * 4));
  float* l1x = (float*)(ws + take(BB * TOPK * 4));
  float* l1y = (float*)(ws + take(BB * TOPK * 4));
  int*   n1 = (int*)(ws + take(BB * 4));
  float* l2x = (float*)(ws + take(BB * TOPK * 4));
  float* l2y = (float*)(ws + take(BB * TOPK * 4));
  int*   n2 = (int*)(ws + take(BB * 4));
  uint32_t* cnt0 = (uint32_t*)(ws + take(BB * NSEG * 4));
  uint32_t* cnt2 = (uint32_t*)(ws + take(BB * NSEG * 4));
  long long* sxq = (long long*)(ws + take(BB * NSEG * 8));
  long long* syq = (long long*)(ws + take(BB * NSEG * 8));
  uint32_t* hist = (uint32_t*)(ws + take((size_t)BB * NSEG * NCC * 4));
  int* instc = (int*)(ws + take(BB * NSEG * 4));
  long long* Ssel = (long long*)(ws + take(BB * NSEG * 8));
  size_t zero_end = off;

  if (ws_size < off) return;  // workspace too small -> fail visibly

  int nsm = (int)((zero_end - zero_begin) / 16);   // 256-aligned span -> uint4 count
  k_clear<<<BB * NPIX / 4 / 256, 256, 0, stream>>>((uint4*)labA,
      (uint4*)(ws + zero_begin), nsm, ymin, ymax, xmin, xmax);

  k_pixel<<<BB * NPIX / 4 / 256, 256, 0, stream>>>(seg, cr, out_segmap,
      (uint32_t*)labA, mbuf, invs, segc);
  k_nms<<<BB * NPIX / 4 / 256, 256, 0, stream>>>((const uint32_t*)labA,
      cand_cnt, cand_val, cand_idx);
  k_topk<<<BB, 256, 0, stream>>>(cand_cnt, cand_val, cand_idx, slotx, sloty, n0);

  dim3 rgrid(HH, BB);                              // one row per block

  // pass 0: all top-k candidates (fallback 0) + cnt/bbox stats
  k_assign0<<<rgrid, 256, 0, stream>>>(cr, segc, slotx, sloty, n0, labA,
      cnt0, ymin, ymax, xmin, xmax);
  k_build1<<<BB, 256, 0, stream>>>(cnt0, ymin, ymax, xmin, xmax, slotx, sloty, l1x, l1y, n1);
  // pass 1: ratio-pruned compact list (fallback lab0) + cnt/cr-sum stats
  k_assign1<<<rgrid, 256, 0, stream>>>(cr, segc, l1x, l1y, n1, labA, labB, cnt2, sxq, syq);
  k_build2<<<BB, 256, 0, stream>>>(cnt2, sxq, syq, slotx, sloty, l2x, l2y, n2);
  // pass 2: mean-pruned compact list (fallback lab1) + final write + histogram
  k_assign2<<<dim3(128, BB), 256, 0, stream>>>(cr, segc, l2x, l2y, n2, labB, labA,
      out_final, hist);

  k_mode<<<BB, 256, 0, stream>>>(hist, instc, out_instc, out_cntf);
  k_sg<<<dim3(NPIX / 1024, BB), 256, 0, stream>>>(seg, labA, instc, mbuf, invs, Ssel);
  k_prob<<<(BB * NSEG + 255) / 256, 256, 0, stream>>>(Ssel, out_cntf, out_prob);
}